// Round 1
// baseline (471.929 us; speedup 1.0000x reference)
//
#include <hip/hip_runtime.h>
#include <hip/hip_bf16.h>
#include <cstdint>
#include <cstddef>

#define BB 16384

typedef float  floatx4 __attribute__((ext_vector_type(4)));
typedef __bf16 bf16x8  __attribute__((ext_vector_type(8)));

__device__ __forceinline__ unsigned short f2bf(float f) {
  union { float f; unsigned int u; } v; v.f = f;
  unsigned int r = v.u + 0x7FFFu + ((v.u >> 16) & 1u);
  return (unsigned short)(r >> 16);
}
__device__ __forceinline__ float bf2f(unsigned short h) {
  union { unsigned int u; float f; } v; v.u = ((unsigned int)h) << 16;
  return v.f;
}
__device__ __forceinline__ float gelu_exact(float x) {
  return 0.5f * x * (1.0f + erff(x * 0.7071067811865475f));
}

// ---------------------------------------------------------------------------
// Weight pack: transpose to N-major bf16 (GEMM wants B^T), plus item_mm->bf16
// ---------------------------------------------------------------------------
__global__ void k_pack(const float* __restrict__ w1, const float* __restrict__ w2,
                       const float* __restrict__ mm_w, const float* __restrict__ gnn_W,
                       const float* __restrict__ bi_W, const float* __restrict__ item_mm,
                       unsigned short* __restrict__ w1t, unsigned short* __restrict__ w2t,
                       unsigned short* __restrict__ mmwt, unsigned short* __restrict__ wallt,
                       unsigned short* __restrict__ biwt, unsigned short* __restrict__ immb)
{
  const int total = 3719168;
  for (int id = blockIdx.x * 256 + threadIdx.x; id < total; id += gridDim.x * 256) {
    if (id < 1376256) {                       // w1t[n][k], n<512,k<2688
      int n = id / 2688, k = id % 2688;
      w1t[id] = f2bf(w1[k * 512 + n]);
    } else if (id < 1507328) {                // w2t[n][k], n<256,k<512
      int l = id - 1376256; int n = l / 512, k = l % 512;
      w2t[l] = f2bf(w2[k * 256 + n]);
    } else if (id < 1523712) {                // mmwt[n][k]
      int l = id - 1507328; int n = l / 128, k = l % 128;
      mmwt[l] = f2bf(mm_w[k * 128 + n]);
    } else if (id < 1540096) {                // wallt[ncol][k], ncol=h*32+o
      int l = id - 1523712; int nc = l / 128, k = l % 128;
      wallt[l] = f2bf(gnn_W[(nc >> 5) * 4096 + k * 32 + (nc & 31)]);
    } else if (id < 1622016) {                // biwt[f][e][d] <- bi_W[f][d][e]
      int l = id - 1540096; int f = l / 16384, rr = l % 16384, e = rr / 128, d = rr % 128;
      biwt[l] = f2bf(bi_W[f * 16384 + d * 128 + e]);
    } else {                                  // immb bf16 copy
      int l = id - 1622016;
      immb[l] = f2bf(item_mm[l]);
    }
  }
}

// ---------------------------------------------------------------------------
// Generic bf16 MFMA GEMM: C[M,N] = A[M,K] * Bt[N,K]^T.  128x128 tile, BK=32.
// EPI: 0 = +bias -> f32 | 1 = f32 | 2 = bf16 | 3 = bias+bn+gelu -> bf16
//      4 = bias+bn+gelu -> f32
// ---------------------------------------------------------------------------
template<int EPI>
__global__ __launch_bounds__(256)
void gemm_bt(const unsigned short* __restrict__ A, int lda, long long sAz,
             const unsigned short* __restrict__ Bt, int ldb, long long sBz,
             void* __restrict__ Cp, int ldc, long long sCz, int K,
             const float* __restrict__ bias, const float* __restrict__ bng,
             const float* __restrict__ bnb)
{
  const int z = blockIdx.z;
  A  += (size_t)((long long)z * sAz);
  Bt += (size_t)((long long)z * sBz);
  const int n0 = blockIdx.x * 128;
  const int m0 = blockIdx.y * 128;
  __shared__ __align__(16) unsigned short As[128 * 32];
  __shared__ __align__(16) unsigned short Bs[128 * 32];
  const int t = threadIdx.x;
  const int lane = t & 63, w = t >> 6;
  const int wm = w & 1, wn = w >> 1;
  const int lr = lane & 15, lq = lane >> 4;

  floatx4 acc[4][4];
  #pragma unroll
  for (int a = 0; a < 4; a++)
    #pragma unroll
    for (int b = 0; b < 4; b++) acc[a][b] = (floatx4){0.f, 0.f, 0.f, 0.f};

  const int r = t >> 1, hh = (t & 1) * 16;      // thread stages 32B of A, 32B of B
  const unsigned short* Ag = A + (size_t)(m0 + r) * lda + hh;
  const unsigned short* Bg = Bt + (size_t)(n0 + r) * ldb + hh;
  unsigned short* Asw = &As[r * 32 + hh];
  unsigned short* Bsw = &Bs[r * 32 + hh];

  for (int k0 = 0; k0 < K; k0 += 32) {
    uint4 a0 = *(const uint4*)(Ag + k0);
    uint4 a1 = *(const uint4*)(Ag + k0 + 8);
    uint4 b0 = *(const uint4*)(Bg + k0);
    uint4 b1 = *(const uint4*)(Bg + k0 + 8);
    __syncthreads();
    *(uint4*)(Asw) = a0; *(uint4*)(Asw + 8) = a1;
    *(uint4*)(Bsw) = b0; *(uint4*)(Bsw + 8) = b1;
    __syncthreads();
    bf16x8 af[4], bfv[4];
    #pragma unroll
    for (int mt = 0; mt < 4; mt++)
      af[mt] = __builtin_bit_cast(bf16x8, *(const uint4*)&As[(wm*64 + mt*16 + lr)*32 + lq*8]);
    #pragma unroll
    for (int nt = 0; nt < 4; nt++)
      bfv[nt] = __builtin_bit_cast(bf16x8, *(const uint4*)&Bs[(wn*64 + nt*16 + lr)*32 + lq*8]);
    #pragma unroll
    for (int mt = 0; mt < 4; mt++)
      #pragma unroll
      for (int nt = 0; nt < 4; nt++)
        acc[mt][nt] = __builtin_amdgcn_mfma_f32_16x16x32_bf16(af[mt], bfv[nt], acc[mt][nt], 0, 0, 0);
  }

  #pragma unroll
  for (int mt = 0; mt < 4; mt++)
    #pragma unroll
    for (int nt = 0; nt < 4; nt++)
      #pragma unroll
      for (int i = 0; i < 4; i++) {
        const int cm = m0 + wm * 64 + mt * 16 + lq * 4 + i;   // row = quad*4+reg
        const int cn = n0 + wn * 64 + nt * 16 + lr;           // col = lane&15
        float v = acc[mt][nt][i];
        size_t idx = (size_t)((long long)z * sCz) + (size_t)cm * ldc + cn;
        if constexpr (EPI == 0) {
          ((float*)Cp)[idx] = v + bias[cn];
        } else if constexpr (EPI == 1) {
          ((float*)Cp)[idx] = v;
        } else if constexpr (EPI == 2) {
          ((unsigned short*)Cp)[idx] = f2bf(v);
        } else {
          float tt = v + bias[cn];
          tt = tt * (bng[cn] * 0.9999950000374997f) + bnb[cn];  // g/sqrt(1+1e-5)
          tt = gelu_exact(tt);
          if constexpr (EPI == 3) ((unsigned short*)Cp)[idx] = f2bf(tt);
          else                    ((float*)Cp)[idx] = tt;
        }
      }
}

// ---------------------------------------------------------------------------
// Feature build: xb rows 0 (zeros), 1,2 (cate), 3 (id), 5 (masked hist mean)
// one wave per batch row; lane covers d and d+64
// ---------------------------------------------------------------------------
__global__ __launch_bounds__(256)
void k_feat(const int* __restrict__ item_id, const int* __restrict__ likes,
            const int* __restrict__ views, const int* __restrict__ item_seq,
            const float* __restrict__ item_emb, const float* __restrict__ cate_emb,
            unsigned short* __restrict__ xb)
{
  const int b = blockIdx.x * 4 + (threadIdx.x >> 6);
  const int lane = threadIdx.x & 63;
  const size_t base = (size_t)b * 768;
  const int li = likes[b], vi = views[b], id = item_id[b];

  float h0 = 0.f, h1 = 0.f, cnt = 0.f;
  for (int l = 0; l < 50; l++) {
    int idx = item_seq[b * 50 + l];
    if (idx != 0) {
      cnt += 1.0f;
      h0 += item_emb[(size_t)idx * 128 + lane];
      h1 += item_emb[(size_t)idx * 128 + lane + 64];
    }
  }
  float ic = 1.0f / fmaxf(cnt, 1.0f);

  xb[base + lane] = 0; xb[base + lane + 64] = 0;                         // user_feat
  xb[base + 128 + lane]      = f2bf(cate_emb[li * 128 + lane]);
  xb[base + 128 + lane + 64] = f2bf(cate_emb[li * 128 + lane + 64]);
  xb[base + 256 + lane]      = f2bf(cate_emb[vi * 128 + lane]);
  xb[base + 256 + lane + 64] = f2bf(cate_emb[vi * 128 + lane + 64]);
  xb[base + 384 + lane]      = f2bf(item_emb[(size_t)id * 128 + lane]);
  xb[base + 384 + lane + 64] = f2bf(item_emb[(size_t)id * 128 + lane + 64]);
  xb[base + 640 + lane]      = f2bf(h0 * ic);
  xb[base + 640 + lane + 64] = f2bf(h1 * ic);
}

// ---------------------------------------------------------------------------
// LayerNorm + exact GELU on y -> xb row 4 (img_feat). one wave per row.
// ---------------------------------------------------------------------------
__global__ __launch_bounds__(256)
void k_ln(const float* __restrict__ y, const float* __restrict__ ln_g,
          const float* __restrict__ ln_b, unsigned short* __restrict__ xb)
{
  const int b = blockIdx.x * 4 + (threadIdx.x >> 6);
  const int lane = threadIdx.x & 63;
  float v0 = y[(size_t)b * 128 + lane], v1 = y[(size_t)b * 128 + lane + 64];
  float s = v0 + v1, s2 = v0 * v0 + v1 * v1;
  #pragma unroll
  for (int o = 32; o > 0; o >>= 1) { s += __shfl_xor(s, o, 64); s2 += __shfl_xor(s2, o, 64); }
  float mu  = s * (1.0f / 128.0f);
  float var = s2 * (1.0f / 128.0f) - mu * mu;
  float rs  = rsqrtf(var + 1e-5f);
  float t0 = (v0 - mu) * rs * ln_g[lane]      + ln_b[lane];
  float t1 = (v1 - mu) * rs * ln_g[lane + 64] + ln_b[lane + 64];
  xb[(size_t)b * 768 + 512 + lane]      = f2bf(gelu_exact(t0));
  xb[(size_t)b * 768 + 512 + lane + 64] = f2bf(gelu_exact(t1));
}

// ---------------------------------------------------------------------------
// GAT attention + residual ELU + SE gate.  one wave per batch row.
// writes gnn_feat(bf16) -> c[:, :768] and s(bf16) -> sb
// ---------------------------------------------------------------------------
__global__ __launch_bounds__(256)
void k_att(const float* __restrict__ hp, const unsigned short* __restrict__ xb,
           const float* __restrict__ gnn_a, const float* __restrict__ se_w1,
           const float* __restrict__ se_b1, const float* __restrict__ se_w2,
           const float* __restrict__ se_b2, unsigned short* __restrict__ c,
           unsigned short* __restrict__ sb)
{
  __shared__ float hps[4][6][128];
  __shared__ float eis[4][4][6], ejs[4][4][6];
  __shared__ float atts[4][4][6][6];
  const int wv = threadIdx.x >> 6, lane = threadIdx.x & 63;
  const int b = blockIdx.x * 4 + wv;

  #pragma unroll
  for (int n = 0; n < 6; n++) {
    hps[wv][n][lane]      = hp[((size_t)b * 6 + n) * 128 + lane];
    hps[wv][n][lane + 64] = hp[((size_t)b * 6 + n) * 128 + lane + 64];
  }
  __syncthreads();

  if (lane < 24) {                      // (h,n) pairs: ei/ej dots over HD=32
    int h = lane & 3, n = lane >> 2;
    float e1 = 0.f, e2 = 0.f;
    for (int o = 0; o < 32; o++) {
      float v = hps[wv][n][h * 32 + o];
      e1 += v * gnn_a[h * 64 + o];
      e2 += v * gnn_a[h * 64 + 32 + o];
    }
    eis[wv][h][n] = e1; ejs[wv][h][n] = e2;
  }
  __syncthreads();

  if (lane < 24) {                      // per (h,i): leaky + softmax over j
    int h = lane & 3, i = lane >> 2;
    float ev[6]; float mx = -1e30f;
    #pragma unroll
    for (int j = 0; j < 6; j++) {
      float e = eis[wv][h][i] + ejs[wv][h][j];
      e = e > 0.f ? e : 0.2f * e;
      ev[j] = e; mx = fmaxf(mx, e);
    }
    float ssum = 0.f;
    #pragma unroll
    for (int j = 0; j < 6; j++) { ev[j] = expf(ev[j] - mx); ssum += ev[j]; }
    float inv = 1.0f / ssum;
    #pragma unroll
    for (int j = 0; j < 6; j++) atts[wv][h][i][j] = ev[j] * inv;
  }
  __syncthreads();

  float gf[6][2];
  float zz[6];
  #pragma unroll
  for (int n = 0; n < 6; n++) {
    float zacc = 0.f;
    #pragma unroll
    for (int u = 0; u < 2; u++) {
      int cidx = lane + u * 64;
      int h = cidx >> 5;
      float hn = 0.f;
      #pragma unroll
      for (int m = 0; m < 6; m++) hn += atts[wv][h][n][m] * hps[wv][m][cidx];
      float xv = bf2f(xb[(size_t)b * 768 + n * 128 + cidx]);
      float g = hn + xv;
      g = g > 0.f ? g : expm1f(g);      // ELU
      gf[n][u] = g; zacc += g;
    }
    #pragma unroll
    for (int o = 32; o > 0; o >>= 1) zacc += __shfl_xor(zacc, o, 64);
    zz[n] = zacc * (1.0f / 128.0f);
  }

  // SE gate (tiny 6->3->6 MLP, computed redundantly per lane)
  float rr[3];
  #pragma unroll
  for (int j = 0; j < 3; j++) {
    float a = se_b1[j];
    #pragma unroll
    for (int n = 0; n < 6; n++) a += zz[n] * se_w1[n * 3 + j];
    rr[j] = fmaxf(a, 0.f);
  }
  float wse[6];
  #pragma unroll
  for (int n = 0; n < 6; n++) {
    float a = se_b2[n];
    #pragma unroll
    for (int j = 0; j < 3; j++) a += rr[j] * se_w2[j * 6 + n];
    wse[n] = 1.0f / (1.0f + expf(-a));
  }

  #pragma unroll
  for (int n = 0; n < 6; n++)
    #pragma unroll
    for (int u = 0; u < 2; u++) {
      int cidx = lane + u * 64;
      c[(size_t)b * 2688 + n * 128 + cidx]  = f2bf(gf[n][u]);
      sb[(size_t)b * 768 + n * 128 + cidx]  = f2bf(gf[n][u] * wse[n]);
    }
}

// ---------------------------------------------------------------------------
// Hadamard pairs: c[:, 768 + p*128 + d] = vid[:, i, d] * s[:, j, d]
// ---------------------------------------------------------------------------
__global__ __launch_bounds__(256)
void k_pairs(const unsigned short* __restrict__ vidb, const unsigned short* __restrict__ sb,
             unsigned short* __restrict__ c)
{
  int gid = blockIdx.x * 256 + threadIdx.x;   // < B*1920
  int b = gid / 1920, rem = gid % 1920;
  int pidx = rem >> 7, d = rem & 127;
  int i, j;
  if      (pidx <  5) { i = 0; j = pidx + 1; }
  else if (pidx <  9) { i = 1; j = pidx - 3; }
  else if (pidx < 12) { i = 2; j = pidx - 6; }
  else if (pidx < 14) { i = 3; j = pidx - 8; }
  else                { i = 4; j = 5; }
  float v = bf2f(vidb[(size_t)b * 640 + i * 128 + d]) * bf2f(sb[(size_t)b * 768 + j * 128 + d]);
  c[(size_t)b * 2688 + 768 + rem] = f2bf(v);
}

// ---------------------------------------------------------------------------
// Final 256-dot + sigmoid. one wave per row.
// ---------------------------------------------------------------------------
__global__ __launch_bounds__(256)
void k_out(const float* __restrict__ h2, const float* __restrict__ w3,
           const float* __restrict__ b3, float* __restrict__ out)
{
  const int b = blockIdx.x * 4 + (threadIdx.x >> 6);
  const int lane = threadIdx.x & 63;
  float a = 0.f;
  #pragma unroll
  for (int u = 0; u < 4; u++) {
    int d = lane + u * 64;
    a += h2[(size_t)b * 256 + d] * w3[d];
  }
  #pragma unroll
  for (int o = 32; o > 0; o >>= 1) a += __shfl_xor(a, o, 64);
  if (lane == 0) out[b] = 1.0f / (1.0f + expf(-(a + b3[0])));
}

// ---------------------------------------------------------------------------
// Workspace layout (bytes). Lifetime-aliased: y=sb region, vid=hp region,
// h1=xb region. Peak ~203 MB.
// ---------------------------------------------------------------------------
#define OFF_W1T    0ull          // 2752512
#define OFF_W2T    2752512ull    // 262144
#define OFF_MMWT   3014656ull    // 32768
#define OFF_WALLT  3047424ull    // 32768
#define OFF_BIWT   3080192ull    // 163840
#define OFF_IMMB   3244032ull    // 4194304
#define OFF_XB     7438336ull    // 25165824  (also h1 later)
#define OFF_HP     32604160ull   // 50331648  (also vid later)
#define OFF_SB     82935808ull   // 25165824  (also y earlier)
#define OFF_C      108101632ull  // 88080384
#define OFF_H2     196182016ull  // 16777216 -> total 212959232

extern "C" void kernel_launch(void* const* d_in, const int* in_sizes, int n_in,
                              void* d_out, int out_size, void* d_ws, size_t ws_size,
                              hipStream_t stream)
{
  const int*   item_id  = (const int*)  d_in[0];
  const float* item_mm  = (const float*)d_in[1];
  const int*   likes    = (const int*)  d_in[2];
  const int*   views    = (const int*)  d_in[3];
  const int*   item_seq = (const int*)  d_in[4];
  const float* item_emb = (const float*)d_in[5];
  const float* cate_emb = (const float*)d_in[6];
  const float* mm_w     = (const float*)d_in[7];
  const float* mm_b     = (const float*)d_in[8];
  const float* ln_g     = (const float*)d_in[9];
  const float* ln_b     = (const float*)d_in[10];
  const float* gnn_W    = (const float*)d_in[11];
  const float* gnn_a    = (const float*)d_in[12];
  const float* se_w1    = (const float*)d_in[13];
  const float* se_b1    = (const float*)d_in[14];
  const float* se_w2    = (const float*)d_in[15];
  const float* se_b2    = (const float*)d_in[16];
  const float* bi_W     = (const float*)d_in[17];
  const float* mlp_w1   = (const float*)d_in[18];
  const float* mlp_b1   = (const float*)d_in[19];
  const float* bn1_g    = (const float*)d_in[20];
  const float* bn1_b    = (const float*)d_in[21];
  const float* mlp_w2   = (const float*)d_in[22];
  const float* mlp_b2   = (const float*)d_in[23];
  const float* bn2_g    = (const float*)d_in[24];
  const float* bn2_b    = (const float*)d_in[25];
  const float* mlp_w3   = (const float*)d_in[26];
  const float* mlp_b3   = (const float*)d_in[27];
  float* out = (float*)d_out;

  char* ws = (char*)d_ws;
  unsigned short* w1t   = (unsigned short*)(ws + OFF_W1T);
  unsigned short* w2t   = (unsigned short*)(ws + OFF_W2T);
  unsigned short* mmwt  = (unsigned short*)(ws + OFF_MMWT);
  unsigned short* wallt = (unsigned short*)(ws + OFF_WALLT);
  unsigned short* biwt  = (unsigned short*)(ws + OFF_BIWT);
  unsigned short* immb  = (unsigned short*)(ws + OFF_IMMB);
  unsigned short* xb    = (unsigned short*)(ws + OFF_XB);
  float*          hpb   = (float*)         (ws + OFF_HP);
  unsigned short* vidb  = (unsigned short*)(ws + OFF_HP);   // alias: hp dead
  unsigned short* sbb   = (unsigned short*)(ws + OFF_SB);
  float*          yb    = (float*)         (ws + OFF_SB);   // alias: y dead before sb
  unsigned short* cbuf  = (unsigned short*)(ws + OFF_C);
  unsigned short* h1b   = (unsigned short*)(ws + OFF_XB);   // alias: xb dead
  float*          h2b   = (float*)         (ws + OFF_H2);

  // 1. pack weights (transposed bf16) + item_mm bf16
  k_pack<<<4096, 256, 0, stream>>>(mlp_w1, mlp_w2, mm_w, gnn_W, bi_W, item_mm,
                                   w1t, w2t, mmwt, wallt, biwt, immb);
  // 2. feature rows 0,1,2,3,5
  k_feat<<<BB / 4, 256, 0, stream>>>(item_id, likes, views, item_seq, item_emb, cate_emb, xb);
  // 3. y = item_mm @ mm_w + mm_b
  gemm_bt<0><<<dim3(1, 128, 1), 256, 0, stream>>>(immb, 128, 0, mmwt, 128, 0,
                                                  yb, 128, 0, 128, mm_b, nullptr, nullptr);
  // 4. LN + GELU -> xb row 4
  k_ln<<<BB / 4, 256, 0, stream>>>(yb, ln_g, ln_b, xb);
  // 5. hp = x2d @ W_all   (M = 6B = 98304)
  gemm_bt<1><<<dim3(1, 768, 1), 256, 0, stream>>>(xb, 128, 0, wallt, 128, 0,
                                                  hpb, 128, 0, 128, nullptr, nullptr, nullptr);
  // 6. attention + SE -> c[:, :768], sb
  k_att<<<BB / 4, 256, 0, stream>>>(hpb, xb, gnn_a, se_w1, se_b1, se_w2, se_b2, cbuf, sbb);
  // 7. vid[f] = s[:, f] @ bi_W[f]  (z-batched over 5)
  gemm_bt<2><<<dim3(1, 128, 5), 256, 0, stream>>>(sbb, 768, 128, biwt, 128, 16384,
                                                  vidb, 640, 128, 128, nullptr, nullptr, nullptr);
  // 8. pairs -> c[:, 768:]
  k_pairs<<<(BB * 1920) / 256, 256, 0, stream>>>(vidb, sbb, cbuf);
  // 9. h1 = gelu(bn1(c @ w1 + b1))
  gemm_bt<3><<<dim3(4, 128, 1), 256, 0, stream>>>(cbuf, 2688, 0, w1t, 2688, 0,
                                                  h1b, 512, 0, 2688, mlp_b1, bn1_g, bn1_b);
  // 10. h2 = gelu(bn2(h1 @ w2 + b2))
  gemm_bt<4><<<dim3(2, 128, 1), 256, 0, stream>>>(h1b, 512, 0, w2t, 512, 0,
                                                  h2b, 256, 0, 512, mlp_b2, bn2_g, bn2_b);
  // 11. out = sigmoid(h2 @ w3 + b3)
  k_out<<<BB / 4, 256, 0, stream>>>(h2b, mlp_w3, mlp_b3, out);
}

// Round 2
// 453.565 us; speedup vs baseline: 1.0405x; 1.0405x over previous
//
#include <hip/hip_runtime.h>
#include <hip/hip_bf16.h>
#include <cstdint>
#include <cstddef>

#define BB 16384

typedef float  floatx4 __attribute__((ext_vector_type(4)));
typedef __bf16 bf16x8  __attribute__((ext_vector_type(8)));

__device__ __forceinline__ unsigned short f2bf(float f) {
  union { float f; unsigned int u; } v; v.f = f;
  unsigned int r = v.u + 0x7FFFu + ((v.u >> 16) & 1u);
  return (unsigned short)(r >> 16);
}
__device__ __forceinline__ float bf2f(unsigned short h) {
  union { unsigned int u; float f; } v; v.u = ((unsigned int)h) << 16;
  return v.f;
}
__device__ __forceinline__ float gelu_exact(float x) {
  return 0.5f * x * (1.0f + erff(x * 0.7071067811865475f));
}

// async global->LDS, 16B per lane; LDS dest is wave-uniform base + lane*16
#define ALOAD16(g, l) \
  __builtin_amdgcn_global_load_lds((const __attribute__((address_space(1))) void*)(g), \
                                   (__attribute__((address_space(3))) void*)(l), 16, 0, 0)

// ---------------------------------------------------------------------------
// Small packs: mm_w^T, gnn_W flat^T, bi_W^T, item_mm bf16
// ---------------------------------------------------------------------------
__global__ void k_pack(const float* __restrict__ mm_w, const float* __restrict__ gnn_W,
                       const float* __restrict__ bi_W, const float* __restrict__ item_mm,
                       unsigned short* __restrict__ mmwt, unsigned short* __restrict__ wallt,
                       unsigned short* __restrict__ biwt, unsigned short* __restrict__ immb)
{
  const int total = 2211840;
  for (int id = blockIdx.x * 256 + threadIdx.x; id < total; id += gridDim.x * 256) {
    if (id < 16384) {                 // mmwt[n][k]
      int n = id / 128, k = id % 128;
      mmwt[id] = f2bf(mm_w[k * 128 + n]);
    } else if (id < 32768) {          // wallt[h*32+o][k]
      int l = id - 16384; int nc = l / 128, k = l % 128;
      wallt[l] = f2bf(gnn_W[(nc >> 5) * 4096 + k * 32 + (nc & 31)]);
    } else if (id < 114688) {         // biwt[f][e][d] <- bi_W[f][d][e]
      int l = id - 32768; int f = l / 16384, rr = l % 16384, e = rr / 128, d = rr % 128;
      biwt[l] = f2bf(bi_W[f * 16384 + d * 128 + e]);
    } else {                          // immb bf16 copy
      int l = id - 114688;
      immb[l] = f2bf(item_mm[l]);
    }
  }
}

// ---------------------------------------------------------------------------
// LDS-tiled transpose: in R x C fp32 -> out C x R bf16.  grid(C/64, R/64), 256 thr
// ---------------------------------------------------------------------------
__global__ __launch_bounds__(256)
void k_transp(const float* __restrict__ in, unsigned short* __restrict__ out, int R, int C)
{
  __shared__ float tile[64][65];
  const int c0 = blockIdx.x * 64, r0 = blockIdx.y * 64;
  const int lr = threadIdx.x >> 6;     // 0..3
  const int lc = threadIdx.x & 63;
  #pragma unroll
  for (int i = 0; i < 16; i++) {
    int r = lr + i * 4;
    tile[r][lc] = in[(size_t)(r0 + r) * C + c0 + lc];
  }
  __syncthreads();
  #pragma unroll
  for (int i = 0; i < 16; i++) {
    int c = lr + i * 4;
    out[(size_t)(c0 + c) * R + r0 + lc] = f2bf(tile[lc][c]);
  }
}

// ---------------------------------------------------------------------------
// Generic bf16 MFMA GEMM: C[M,N] = A[M,K] * Bt[N,K]^T.  128x128 tile, BK=32,
// global_load_lds(16B) staging.  SWZ: XCD-affinity block swizzle.
// EPI: 0 = +bias -> f32 | 1 = f32 | 2 = bf16 | 3 = bias+bn+gelu -> bf16
//      5 = vid*s pairs fused (uses sbx, writes bf16 pairs into Cp)
// ---------------------------------------------------------------------------
template<int EPI, bool SWZ>
__global__ __launch_bounds__(256)
void gemm_bt(const unsigned short* __restrict__ A, int lda, long long sAz,
             const unsigned short* __restrict__ Bt, int ldb, long long sBz,
             void* __restrict__ Cp, int ldc, long long sCz, int K,
             const float* __restrict__ bias, const float* __restrict__ bng,
             const float* __restrict__ bnb, const unsigned short* __restrict__ sbx)
{
  int bx = blockIdx.x, by = blockIdx.y;
  if constexpr (SWZ) {
    int p = by * gridDim.x + bx;
    int xcd = p & 7, slot = p >> 3;
    bx = slot % gridDim.x;
    by = xcd * (gridDim.y >> 3) + slot / gridDim.x;
  }
  const int z = blockIdx.z;
  A  += (long long)z * sAz;
  Bt += (long long)z * sBz;
  const int n0 = bx * 128;
  const int m0 = by * 128;
  __shared__ __align__(16) unsigned short As[128 * 32];
  __shared__ __align__(16) unsigned short Bs[128 * 32];
  const int t = threadIdx.x;
  const int lane = t & 63, w = t >> 6;
  const int wm = w & 1, wn = w >> 1;
  const int lr = lane & 15, lq = lane >> 4;

  floatx4 acc[4][4];
  #pragma unroll
  for (int a = 0; a < 4; a++)
    #pragma unroll
    for (int b = 0; b < 4; b++) acc[a][b] = (floatx4){0.f, 0.f, 0.f, 0.f};

  // staging: wave w covers rows w*32..w*32+31 (two 16-row issues each for A,B)
  const int sr = lane >> 2, sc = (lane & 3) * 8;
  const unsigned short* Ag = A + (size_t)(m0 + w * 32 + sr) * lda + sc;
  const unsigned short* Bg = Bt + (size_t)(n0 + w * 32 + sr) * ldb + sc;
  unsigned short* AsW = As + w * 32 * 32;
  unsigned short* BsW = Bs + w * 32 * 32;

  for (int k0 = 0; k0 < K; k0 += 32) {
    __syncthreads();   // previous tile fully consumed
    ALOAD16(Ag + k0,                       AsW);
    ALOAD16(Ag + k0 + (size_t)16 * lda,    AsW + 16 * 32);
    ALOAD16(Bg + k0,                       BsW);
    ALOAD16(Bg + k0 + (size_t)16 * ldb,    BsW + 16 * 32);
    __syncthreads();   // loads drained (vmcnt before barrier)
    bf16x8 af[4], bfv[4];
    #pragma unroll
    for (int mt = 0; mt < 4; mt++)
      af[mt] = __builtin_bit_cast(bf16x8, *(const uint4*)&As[(wm*64 + mt*16 + lr)*32 + lq*8]);
    #pragma unroll
    for (int nt = 0; nt < 4; nt++)
      bfv[nt] = __builtin_bit_cast(bf16x8, *(const uint4*)&Bs[(wn*64 + nt*16 + lr)*32 + lq*8]);
    #pragma unroll
    for (int mt = 0; mt < 4; mt++)
      #pragma unroll
      for (int nt = 0; nt < 4; nt++)
        acc[mt][nt] = __builtin_amdgcn_mfma_f32_16x16x32_bf16(af[mt], bfv[nt], acc[mt][nt], 0, 0, 0);
  }

  #pragma unroll
  for (int mt = 0; mt < 4; mt++)
    #pragma unroll
    for (int nt = 0; nt < 4; nt++)
      #pragma unroll
      for (int i = 0; i < 4; i++) {
        const int cm = m0 + wm * 64 + mt * 16 + lq * 4 + i;   // row = quad*4+reg
        const int cn = n0 + wn * 64 + nt * 16 + lr;           // col = lane&15
        float v = acc[mt][nt][i];
        size_t idx = (size_t)((long long)z * sCz) + (size_t)cm * ldc + cn;
        if constexpr (EPI == 0) {
          ((float*)Cp)[idx] = v + bias[cn];
        } else if constexpr (EPI == 1) {
          ((float*)Cp)[idx] = v;
        } else if constexpr (EPI == 2) {
          ((unsigned short*)Cp)[idx] = f2bf(v);
        } else if constexpr (EPI == 3) {
          float tt = v + bias[cn];
          tt = tt * (bng[cn] * 0.9999950000374997f) + bnb[cn];  // g/sqrt(1+1e-5)
          ((unsigned short*)Cp)[idx] = f2bf(gelu_exact(tt));
        } else {  // EPI == 5: vid (z = feature i) -> pairs with s[:, j], j > z
          const int pb0[5] = {0, 5, 9, 12, 14};
          unsigned short* c = (unsigned short*)Cp;
          for (int j = z + 1; j < 6; j++) {
            float sv = bf2f(sbx[(size_t)cm * 768 + j * 128 + cn]);
            int p = pb0[z] + (j - z - 1);
            c[(size_t)cm * 2688 + 768 + (size_t)p * 128 + cn] = f2bf(v * sv);
          }
        }
      }
}

// ---------------------------------------------------------------------------
// Feature build, float4-vectorized: rows 0(zeros),1,2(cate),3(id),5(hist mean)
// one wave per batch row; half-waves split seq entries / output rows
// ---------------------------------------------------------------------------
__global__ __launch_bounds__(256)
void k_feat(const int* __restrict__ item_id, const int* __restrict__ likes,
            const int* __restrict__ views, const int* __restrict__ item_seq,
            const float* __restrict__ item_emb, const float* __restrict__ cate_emb,
            unsigned short* __restrict__ xb)
{
  const int b = blockIdx.x * 4 + (threadIdx.x >> 6);
  const int lane = threadIdx.x & 63;
  const int half = lane >> 5, ql = lane & 31;
  const size_t base = (size_t)b * 768;
  const int li = likes[b], vi = views[b], id = item_id[b];

  float4 hs = make_float4(0.f, 0.f, 0.f, 0.f);
  float cnt = 0.f;
  for (int l = half; l < 50; l += 2) {
    int idx = item_seq[b * 50 + l];
    if (idx != 0) {
      cnt += 1.0f;
      const float4 v = *(const float4*)&item_emb[(size_t)idx * 128 + ql * 4];
      hs.x += v.x; hs.y += v.y; hs.z += v.z; hs.w += v.w;
    }
  }
  cnt  += __shfl_xor(cnt, 32, 64);
  hs.x += __shfl_xor(hs.x, 32, 64);
  hs.y += __shfl_xor(hs.y, 32, 64);
  hs.z += __shfl_xor(hs.z, 32, 64);
  hs.w += __shfl_xor(hs.w, 32, 64);
  const float ic = 1.0f / fmaxf(cnt, 1.0f);

  *(unsigned int*)&xb[base + lane * 2] = 0u;            // row 0 zeros

  {                                                     // rows 1,2 (like/view)
    const float4 v = *(const float4*)&cate_emb[(size_t)(half ? vi : li) * 128 + ql * 4];
    ushort4 o; o.x = f2bf(v.x); o.y = f2bf(v.y); o.z = f2bf(v.z); o.w = f2bf(v.w);
    *(ushort4*)&xb[base + 128 + half * 128 + ql * 4] = o;
  }
  if (half == 0) {                                      // row 3 (id)
    const float4 v = *(const float4*)&item_emb[(size_t)id * 128 + ql * 4];
    ushort4 o; o.x = f2bf(v.x); o.y = f2bf(v.y); o.z = f2bf(v.z); o.w = f2bf(v.w);
    *(ushort4*)&xb[base + 384 + ql * 4] = o;
  } else {                                              // row 5 (hist mean)
    ushort4 o; o.x = f2bf(hs.x * ic); o.y = f2bf(hs.y * ic);
               o.z = f2bf(hs.z * ic); o.w = f2bf(hs.w * ic);
    *(ushort4*)&xb[base + 640 + ql * 4] = o;
  }
}

// ---------------------------------------------------------------------------
// LayerNorm + exact GELU on y -> xb row 4 (img_feat). one wave per row.
// ---------------------------------------------------------------------------
__global__ __launch_bounds__(256)
void k_ln(const float* __restrict__ y, const float* __restrict__ ln_g,
          const float* __restrict__ ln_b, unsigned short* __restrict__ xb)
{
  const int b = blockIdx.x * 4 + (threadIdx.x >> 6);
  const int lane = threadIdx.x & 63;
  float v0 = y[(size_t)b * 128 + lane], v1 = y[(size_t)b * 128 + lane + 64];
  float s = v0 + v1, s2 = v0 * v0 + v1 * v1;
  #pragma unroll
  for (int o = 32; o > 0; o >>= 1) { s += __shfl_xor(s, o, 64); s2 += __shfl_xor(s2, o, 64); }
  float mu  = s * (1.0f / 128.0f);
  float var = s2 * (1.0f / 128.0f) - mu * mu;
  float rs  = rsqrtf(var + 1e-5f);
  float t0 = (v0 - mu) * rs * ln_g[lane]      + ln_b[lane];
  float t1 = (v1 - mu) * rs * ln_g[lane + 64] + ln_b[lane + 64];
  xb[(size_t)b * 768 + 512 + lane]      = f2bf(gelu_exact(t0));
  xb[(size_t)b * 768 + 512 + lane + 64] = f2bf(gelu_exact(t1));
}

// ---------------------------------------------------------------------------
// GAT attention + residual ELU + SE gate.  one wave per batch row.
// hp is bf16 now.  writes gnn_feat(bf16) -> c[:, :768] and s(bf16) -> sb
// ---------------------------------------------------------------------------
__global__ __launch_bounds__(256)
void k_att(const unsigned short* __restrict__ hp, const unsigned short* __restrict__ xb,
           const float* __restrict__ gnn_a, const float* __restrict__ se_w1,
           const float* __restrict__ se_b1, const float* __restrict__ se_w2,
           const float* __restrict__ se_b2, unsigned short* __restrict__ c,
           unsigned short* __restrict__ sb)
{
  __shared__ float hps[4][6][128];
  __shared__ float eis[4][4][6], ejs[4][4][6];
  __shared__ float atts[4][4][6][6];
  const int wv = threadIdx.x >> 6, lane = threadIdx.x & 63;
  const int b = blockIdx.x * 4 + wv;

  #pragma unroll
  for (int n = 0; n < 6; n++) {
    unsigned int pk = *(const unsigned int*)&hp[((size_t)b * 6 + n) * 128 + lane * 2];
    hps[wv][n][lane * 2]     = bf2f((unsigned short)(pk & 0xFFFFu));
    hps[wv][n][lane * 2 + 1] = bf2f((unsigned short)(pk >> 16));
  }
  __syncthreads();

  if (lane < 24) {                      // (h,n) pairs: ei/ej dots over HD=32
    int h = lane & 3, n = lane >> 2;
    float e1 = 0.f, e2 = 0.f;
    for (int o = 0; o < 32; o++) {
      float v = hps[wv][n][h * 32 + o];
      e1 += v * gnn_a[h * 64 + o];
      e2 += v * gnn_a[h * 64 + 32 + o];
    }
    eis[wv][h][n] = e1; ejs[wv][h][n] = e2;
  }
  __syncthreads();

  if (lane < 24) {                      // per (h,i): leaky + softmax over j
    int h = lane & 3, i = lane >> 2;
    float ev[6]; float mx = -1e30f;
    #pragma unroll
    for (int j = 0; j < 6; j++) {
      float e = eis[wv][h][i] + ejs[wv][h][j];
      e = e > 0.f ? e : 0.2f * e;
      ev[j] = e; mx = fmaxf(mx, e);
    }
    float ssum = 0.f;
    #pragma unroll
    for (int j = 0; j < 6; j++) { ev[j] = expf(ev[j] - mx); ssum += ev[j]; }
    float inv = 1.0f / ssum;
    #pragma unroll
    for (int j = 0; j < 6; j++) atts[wv][h][i][j] = ev[j] * inv;
  }
  __syncthreads();

  float gf[6][2];
  float zz[6];
  #pragma unroll
  for (int n = 0; n < 6; n++) {
    float zacc = 0.f;
    #pragma unroll
    for (int u = 0; u < 2; u++) {
      int cidx = lane + u * 64;
      int h = cidx >> 5;
      float hn = 0.f;
      #pragma unroll
      for (int m = 0; m < 6; m++) hn += atts[wv][h][n][m] * hps[wv][m][cidx];
      float xv = bf2f(xb[(size_t)b * 768 + n * 128 + cidx]);
      float g = hn + xv;
      g = g > 0.f ? g : expm1f(g);      // ELU
      gf[n][u] = g; zacc += g;
    }
    #pragma unroll
    for (int o = 32; o > 0; o >>= 1) zacc += __shfl_xor(zacc, o, 64);
    zz[n] = zacc * (1.0f / 128.0f);
  }

  // SE gate (tiny 6->3->6 MLP, redundant per lane)
  float rr[3];
  #pragma unroll
  for (int j = 0; j < 3; j++) {
    float a = se_b1[j];
    #pragma unroll
    for (int n = 0; n < 6; n++) a += zz[n] * se_w1[n * 3 + j];
    rr[j] = fmaxf(a, 0.f);
  }
  float wse[6];
  #pragma unroll
  for (int n = 0; n < 6; n++) {
    float a = se_b2[n];
    #pragma unroll
    for (int j = 0; j < 3; j++) a += rr[j] * se_w2[j * 6 + n];
    wse[n] = 1.0f / (1.0f + expf(-a));
  }

  #pragma unroll
  for (int n = 0; n < 6; n++)
    #pragma unroll
    for (int u = 0; u < 2; u++) {
      int cidx = lane + u * 64;
      c[(size_t)b * 2688 + n * 128 + cidx] = f2bf(gf[n][u]);
      sb[(size_t)b * 768 + n * 128 + cidx] = f2bf(gf[n][u] * wse[n]);
    }
}

// ---------------------------------------------------------------------------
// Final 256-dot + sigmoid (h2 bf16). one wave per row.
// ---------------------------------------------------------------------------
__global__ __launch_bounds__(256)
void k_out(const unsigned short* __restrict__ h2, const float* __restrict__ w3,
           const float* __restrict__ b3, float* __restrict__ out)
{
  const int b = blockIdx.x * 4 + (threadIdx.x >> 6);
  const int lane = threadIdx.x & 63;
  ushort4 v = *(const ushort4*)&h2[(size_t)b * 256 + lane * 4];
  float a = bf2f(v.x) * w3[lane * 4]     + bf2f(v.y) * w3[lane * 4 + 1]
          + bf2f(v.z) * w3[lane * 4 + 2] + bf2f(v.w) * w3[lane * 4 + 3];
  #pragma unroll
  for (int o = 32; o > 0; o >>= 1) a += __shfl_xor(a, o, 64);
  if (lane == 0) out[b] = 1.0f / (1.0f + expf(-(a + b3[0])));
}

// ---------------------------------------------------------------------------
// Workspace layout (bytes). Aliases: y=sb region, h1=xb region. Peak ~179 MB.
// ---------------------------------------------------------------------------
#define OFF_MMWT   0ull           // 32768
#define OFF_WALLT  32768ull       // 32768
#define OFF_BIWT   65536ull       // 163840
#define OFF_W1T    229376ull      // 2752512
#define OFF_W2T    2981888ull     // 262144
#define OFF_IMMB   3244032ull     // 4194304
#define OFF_XB     7438336ull     // 25165824  (alias: h1 16777216 later)
#define OFF_HP     32604160ull    // 25165824  (bf16 now)
#define OFF_SB     57769984ull    // 25165824  (alias: y 8388608 earlier)
#define OFF_C      82935808ull    // 88080384
#define OFF_H2     171016192ull   // 8388608 -> total 179404800

extern "C" void kernel_launch(void* const* d_in, const int* in_sizes, int n_in,
                              void* d_out, int out_size, void* d_ws, size_t ws_size,
                              hipStream_t stream)
{
  const int*   item_id  = (const int*)  d_in[0];
  const float* item_mm  = (const float*)d_in[1];
  const int*   likes    = (const int*)  d_in[2];
  const int*   views    = (const int*)  d_in[3];
  const int*   item_seq = (const int*)  d_in[4];
  const float* item_emb = (const float*)d_in[5];
  const float* cate_emb = (const float*)d_in[6];
  const float* mm_w     = (const float*)d_in[7];
  const float* mm_b     = (const float*)d_in[8];
  const float* ln_g     = (const float*)d_in[9];
  const float* ln_b     = (const float*)d_in[10];
  const float* gnn_W    = (const float*)d_in[11];
  const float* gnn_a    = (const float*)d_in[12];
  const float* se_w1    = (const float*)d_in[13];
  const float* se_b1    = (const float*)d_in[14];
  const float* se_w2    = (const float*)d_in[15];
  const float* se_b2    = (const float*)d_in[16];
  const float* bi_W     = (const float*)d_in[17];
  const float* mlp_w1   = (const float*)d_in[18];
  const float* mlp_b1   = (const float*)d_in[19];
  const float* bn1_g    = (const float*)d_in[20];
  const float* bn1_b    = (const float*)d_in[21];
  const float* mlp_w2   = (const float*)d_in[22];
  const float* mlp_b2   = (const float*)d_in[23];
  const float* bn2_g    = (const float*)d_in[24];
  const float* bn2_b    = (const float*)d_in[25];
  const float* mlp_w3   = (const float*)d_in[26];
  const float* mlp_b3   = (const float*)d_in[27];
  float* out = (float*)d_out;

  char* ws = (char*)d_ws;
  unsigned short* mmwt  = (unsigned short*)(ws + OFF_MMWT);
  unsigned short* wallt = (unsigned short*)(ws + OFF_WALLT);
  unsigned short* biwt  = (unsigned short*)(ws + OFF_BIWT);
  unsigned short* w1t   = (unsigned short*)(ws + OFF_W1T);
  unsigned short* w2t   = (unsigned short*)(ws + OFF_W2T);
  unsigned short* immb  = (unsigned short*)(ws + OFF_IMMB);
  unsigned short* xb    = (unsigned short*)(ws + OFF_XB);
  unsigned short* hpb   = (unsigned short*)(ws + OFF_HP);
  unsigned short* sbb   = (unsigned short*)(ws + OFF_SB);
  float*          yb    = (float*)         (ws + OFF_SB);   // alias: dead before sb
  unsigned short* cbuf  = (unsigned short*)(ws + OFF_C);
  unsigned short* h1b   = (unsigned short*)(ws + OFF_XB);   // alias: xb dead
  unsigned short* h2b   = (unsigned short*)(ws + OFF_H2);

  // 1. small packs
  k_pack<<<2048, 256, 0, stream>>>(mm_w, gnn_W, bi_W, item_mm, mmwt, wallt, biwt, immb);
  // 2-3. coalesced transposes of mlp_w1, mlp_w2
  k_transp<<<dim3(8, 42), 256, 0, stream>>>(mlp_w1, w1t, 2688, 512);
  k_transp<<<dim3(4, 8),  256, 0, stream>>>(mlp_w2, w2t, 512, 256);
  // 4. feature rows 0,1,2,3,5
  k_feat<<<BB / 4, 256, 0, stream>>>(item_id, likes, views, item_seq, item_emb, cate_emb, xb);
  // 5. y = item_mm @ mm_w + mm_b
  gemm_bt<0, false><<<dim3(1, 128, 1), 256, 0, stream>>>(immb, 128, 0, mmwt, 128, 0,
      yb, 128, 0, 128, mm_b, nullptr, nullptr, nullptr);
  // 6. LN + GELU -> xb row 4
  k_ln<<<BB / 4, 256, 0, stream>>>(yb, ln_g, ln_b, xb);
  // 7. hp = x2d @ W_all (bf16 out)
  gemm_bt<2, false><<<dim3(1, 768, 1), 256, 0, stream>>>(xb, 128, 0, wallt, 128, 0,
      hpb, 128, 0, 128, nullptr, nullptr, nullptr, nullptr);
  // 8. attention + SE -> c[:, :768], sb
  k_att<<<BB / 4, 256, 0, stream>>>(hpb, xb, gnn_a, se_w1, se_b1, se_w2, se_b2, cbuf, sbb);
  // 9. vid GEMM + fused pairs -> c[:, 768:]
  gemm_bt<5, false><<<dim3(1, 128, 5), 256, 0, stream>>>(sbb, 768, 128, biwt, 128, 16384,
      cbuf, 0, 0, 128, nullptr, nullptr, nullptr, sbb);
  // 10. h1 = gelu(bn1(c @ w1 + b1))
  gemm_bt<3, true><<<dim3(4, 128, 1), 256, 0, stream>>>(cbuf, 2688, 0, w1t, 2688, 0,
      h1b, 512, 0, 2688, mlp_b1, bn1_g, bn1_b, nullptr);
  // 11. h2 = gelu(bn2(h1 @ w2 + b2))
  gemm_bt<3, true><<<dim3(2, 128, 1), 256, 0, stream>>>(h1b, 512, 0, w2t, 512, 0,
      h2b, 256, 0, 512, mlp_b2, bn2_g, bn2_b, nullptr);
  // 12. out = sigmoid(h2 @ w3 + b3)
  k_out<<<BB / 4, 256, 0, stream>>>(h2b, mlp_w3, mlp_b3, out);
}

// Round 3
// 391.427 us; speedup vs baseline: 1.2057x; 1.1587x over previous
//
#include <hip/hip_runtime.h>
#include <hip/hip_bf16.h>
#include <cstdint>
#include <cstddef>

#define BB 16384

typedef float  floatx4 __attribute__((ext_vector_type(4)));
typedef __bf16 bf16x8  __attribute__((ext_vector_type(8)));

__device__ __forceinline__ unsigned short f2bf(float f) {
  union { float f; unsigned int u; } v; v.f = f;
  unsigned int r = v.u + 0x7FFFu + ((v.u >> 16) & 1u);
  return (unsigned short)(r >> 16);
}
__device__ __forceinline__ float bf2f(unsigned short h) {
  union { unsigned int u; float f; } v; v.u = ((unsigned int)h) << 16;
  return v.f;
}
__device__ __forceinline__ float gelu_exact(float x) {
  return 0.5f * x * (1.0f + erff(x * 0.7071067811865475f));
}

// async global->LDS, 16B per lane; LDS dest is wave-uniform base + lane*16
#define ALOAD16(g, l) \
  __builtin_amdgcn_global_load_lds((const __attribute__((address_space(1))) void*)(g), \
                                   (__attribute__((address_space(3))) void*)(l), 16, 0, 0)

// ---------------------------------------------------------------------------
// Small packs: mm_w^T, gnn_W flat^T, bi_W^T, item_mm bf16
// ---------------------------------------------------------------------------
__global__ void k_pack(const float* __restrict__ mm_w, const float* __restrict__ gnn_W,
                       const float* __restrict__ bi_W, const float* __restrict__ item_mm,
                       unsigned short* __restrict__ mmwt, unsigned short* __restrict__ wallt,
                       unsigned short* __restrict__ biwt, unsigned short* __restrict__ immb)
{
  const int total = 2211840;
  for (int id = blockIdx.x * 256 + threadIdx.x; id < total; id += gridDim.x * 256) {
    if (id < 16384) {                 // mmwt[n][k]
      int n = id / 128, k = id % 128;
      mmwt[id] = f2bf(mm_w[k * 128 + n]);
    } else if (id < 32768) {          // wallt[h*32+o][k]
      int l = id - 16384; int nc = l / 128, k = l % 128;
      wallt[l] = f2bf(gnn_W[(nc >> 5) * 4096 + k * 32 + (nc & 31)]);
    } else if (id < 114688) {         // biwt[f][e][d] <- bi_W[f][d][e]
      int l = id - 32768; int f = l / 16384, rr = l % 16384, e = rr / 128, d = rr % 128;
      biwt[l] = f2bf(bi_W[f * 16384 + d * 128 + e]);
    } else {                          // immb bf16 copy
      int l = id - 114688;
      immb[l] = f2bf(item_mm[l]);
    }
  }
}

// fp32 -> bf16 bulk convert (float4/ushort4), n4 = elems/4
__global__ __launch_bounds__(256)
void k_cvt(const float* __restrict__ in, unsigned short* __restrict__ out, int n4)
{
  int i = blockIdx.x * 256 + threadIdx.x;
  if (i < n4) {
    float4 v = ((const float4*)in)[i];
    ushort4 o; o.x = f2bf(v.x); o.y = f2bf(v.y); o.z = f2bf(v.z); o.w = f2bf(v.w);
    ((ushort4*)out)[i] = o;
  }
}

// ---------------------------------------------------------------------------
// LDS-tiled transpose: in R x C fp32 -> out C x R bf16.  grid(C/64, R/64), 256 thr
// ---------------------------------------------------------------------------
__global__ __launch_bounds__(256)
void k_transp(const float* __restrict__ in, unsigned short* __restrict__ out, int R, int C)
{
  __shared__ float tile[64][65];
  const int c0 = blockIdx.x * 64, r0 = blockIdx.y * 64;
  const int lr = threadIdx.x >> 6;     // 0..3
  const int lc = threadIdx.x & 63;
  #pragma unroll
  for (int i = 0; i < 16; i++) {
    int r = lr + i * 4;
    tile[r][lc] = in[(size_t)(r0 + r) * C + c0 + lc];
  }
  __syncthreads();
  #pragma unroll
  for (int i = 0; i < 16; i++) {
    int c = lr + i * 4;
    out[(size_t)(c0 + c) * R + r0 + lc] = f2bf(tile[lc][c]);
  }
}

// ---------------------------------------------------------------------------
// Generic bf16 MFMA GEMM: C[M,N] = A[M,K] * Bt[N,K]^T.  128x128 tile, BK=32,
// global_load_lds(16B) staging.  SWZ: XCD-affinity block swizzle.
// EPI: 0 = +bias -> f32 | 2 = bf16 | 3 = bias+bn+gelu -> bf16
// ---------------------------------------------------------------------------
template<int EPI, bool SWZ>
__global__ __launch_bounds__(256)
void gemm_bt(const unsigned short* __restrict__ A, int lda,
             const unsigned short* __restrict__ Bt, int ldb,
             void* __restrict__ Cp, int ldc, int K,
             const float* __restrict__ bias, const float* __restrict__ bng,
             const float* __restrict__ bnb)
{
  int bx = blockIdx.x, by = blockIdx.y;
  if constexpr (SWZ) {
    int p = by * gridDim.x + bx;
    int xcd = p & 7, slot = p >> 3;
    bx = slot % gridDim.x;
    by = xcd * (gridDim.y >> 3) + slot / gridDim.x;
  }
  const int n0 = bx * 128;
  const int m0 = by * 128;
  __shared__ __align__(16) unsigned short As[128 * 32];
  __shared__ __align__(16) unsigned short Bs[128 * 32];
  const int t = threadIdx.x;
  const int lane = t & 63, w = t >> 6;
  const int wm = w & 1, wn = w >> 1;
  const int lr = lane & 15, lq = lane >> 4;

  floatx4 acc[4][4];
  #pragma unroll
  for (int a = 0; a < 4; a++)
    #pragma unroll
    for (int b = 0; b < 4; b++) acc[a][b] = (floatx4){0.f, 0.f, 0.f, 0.f};

  const int sr = lane >> 2, sc = (lane & 3) * 8;
  const unsigned short* Ag = A + (size_t)(m0 + w * 32 + sr) * lda + sc;
  const unsigned short* Bg = Bt + (size_t)(n0 + w * 32 + sr) * ldb + sc;
  unsigned short* AsW = As + w * 32 * 32;
  unsigned short* BsW = Bs + w * 32 * 32;

  for (int k0 = 0; k0 < K; k0 += 32) {
    __syncthreads();
    ALOAD16(Ag + k0,                       AsW);
    ALOAD16(Ag + k0 + (size_t)16 * lda,    AsW + 16 * 32);
    ALOAD16(Bg + k0,                       BsW);
    ALOAD16(Bg + k0 + (size_t)16 * ldb,    BsW + 16 * 32);
    __syncthreads();
    bf16x8 af[4], bfv[4];
    #pragma unroll
    for (int mt = 0; mt < 4; mt++)
      af[mt] = __builtin_bit_cast(bf16x8, *(const uint4*)&As[(wm*64 + mt*16 + lr)*32 + lq*8]);
    #pragma unroll
    for (int nt = 0; nt < 4; nt++)
      bfv[nt] = __builtin_bit_cast(bf16x8, *(const uint4*)&Bs[(wn*64 + nt*16 + lr)*32 + lq*8]);
    #pragma unroll
    for (int mt = 0; mt < 4; mt++)
      #pragma unroll
      for (int nt = 0; nt < 4; nt++)
        acc[mt][nt] = __builtin_amdgcn_mfma_f32_16x16x32_bf16(af[mt], bfv[nt], acc[mt][nt], 0, 0, 0);
  }

  #pragma unroll
  for (int mt = 0; mt < 4; mt++)
    #pragma unroll
    for (int nt = 0; nt < 4; nt++)
      #pragma unroll
      for (int i = 0; i < 4; i++) {
        const int cm = m0 + wm * 64 + mt * 16 + lq * 4 + i;   // row = quad*4+reg
        const int cn = n0 + wn * 64 + nt * 16 + lr;           // col = lane&15
        float v = acc[mt][nt][i];
        size_t idx = (size_t)cm * ldc + cn;
        if constexpr (EPI == 0) {
          ((float*)Cp)[idx] = v + bias[cn];
        } else if constexpr (EPI == 2) {
          ((unsigned short*)Cp)[idx] = f2bf(v);
        } else {
          float tt = v + bias[cn];
          tt = tt * (bng[cn] * 0.9999950000374997f) + bnb[cn];  // g/sqrt(1+1e-5)
          ((unsigned short*)Cp)[idx] = f2bf(gelu_exact(tt));
        }
      }
}

// ---------------------------------------------------------------------------
// vid GEMM + pairs, LDS-transposed epilogue.
// grid(1, 128, 5): z = feature i, m0 = by*128 batch rows.
// vid_tile = s[:, z] @ biwt[z]; then pairs p = vid_tile * s[:, j] (j>z),
// written coalesced (ushort4) into c[:, 768 + p*128 + :].
// ---------------------------------------------------------------------------
__global__ __launch_bounds__(256)
void gemm_vid(const unsigned short* __restrict__ sbb, const unsigned short* __restrict__ biwt,
              unsigned short* __restrict__ c)
{
  const int z = blockIdx.z;
  const int m0 = blockIdx.y * 128;
  // LDS: staging (16 KB) reused as vid tile (128 x pad130 bf16 = 33.3 KB)
  __shared__ __align__(16) unsigned short smem[128 * 130];
  unsigned short* As = smem;            // 128*32
  unsigned short* Bs = smem + 4096;     // 128*32
  const int t = threadIdx.x;
  const int lane = t & 63, w = t >> 6;
  const int wm = w & 1, wn = w >> 1;
  const int lr = lane & 15, lq = lane >> 4;

  floatx4 acc[4][4];
  #pragma unroll
  for (int a = 0; a < 4; a++)
    #pragma unroll
    for (int b = 0; b < 4; b++) acc[a][b] = (floatx4){0.f, 0.f, 0.f, 0.f};

  const int sr = lane >> 2, sc = (lane & 3) * 8;
  const unsigned short* Ag = sbb + (size_t)(m0 + w * 32 + sr) * 768 + z * 128 + sc;
  const unsigned short* Bg = biwt + z * 16384 + (size_t)(w * 32 + sr) * 128 + sc;
  unsigned short* AsW = As + w * 32 * 32;
  unsigned short* BsW = Bs + w * 32 * 32;

  for (int k0 = 0; k0 < 128; k0 += 32) {
    __syncthreads();
    ALOAD16(Ag + k0,                  AsW);
    ALOAD16(Ag + k0 + (size_t)16 * 768, AsW + 16 * 32);
    ALOAD16(Bg + k0,                  BsW);
    ALOAD16(Bg + k0 + (size_t)16 * 128, BsW + 16 * 32);
    __syncthreads();
    bf16x8 af[4], bfv[4];
    #pragma unroll
    for (int mt = 0; mt < 4; mt++)
      af[mt] = __builtin_bit_cast(bf16x8, *(const uint4*)&As[(wm*64 + mt*16 + lr)*32 + lq*8]);
    #pragma unroll
    for (int nt = 0; nt < 4; nt++)
      bfv[nt] = __builtin_bit_cast(bf16x8, *(const uint4*)&Bs[(wn*64 + nt*16 + lr)*32 + lq*8]);
    #pragma unroll
    for (int mt = 0; mt < 4; mt++)
      #pragma unroll
      for (int nt = 0; nt < 4; nt++)
        acc[mt][nt] = __builtin_amdgcn_mfma_f32_16x16x32_bf16(af[mt], bfv[nt], acc[mt][nt], 0, 0, 0);
  }

  __syncthreads();                      // staging dead; reuse smem as vid tile
  #pragma unroll
  for (int mt = 0; mt < 4; mt++)
    #pragma unroll
    for (int nt = 0; nt < 4; nt++)
      #pragma unroll
      for (int i = 0; i < 4; i++) {
        const int rr = wm * 64 + mt * 16 + lq * 4 + i;
        const int cc = wn * 64 + nt * 16 + lr;
        smem[rr * 130 + cc] = f2bf(acc[mt][nt][i]);
      }
  __syncthreads();

  const int pb0[5] = {0, 5, 9, 12, 14};
  const int npairs = 5 - z;
  const int tot = 128 * 32 * npairs;    // ushort4 units
  for (int e = t; e < tot; e += 256) {
    const int g  = e & 31;
    const int rp = e >> 5;
    const int p  = rp % npairs;
    const int r  = rp / npairs;
    ushort4 vv = *(const ushort4*)&smem[r * 130 + g * 4];
    ushort4 sv = *(const ushort4*)&sbb[(size_t)(m0 + r) * 768 + (z + 1 + p) * 128 + g * 4];
    ushort4 o;
    o.x = f2bf(bf2f(vv.x) * bf2f(sv.x));
    o.y = f2bf(bf2f(vv.y) * bf2f(sv.y));
    o.z = f2bf(bf2f(vv.z) * bf2f(sv.z));
    o.w = f2bf(bf2f(vv.w) * bf2f(sv.w));
    *(ushort4*)&c[(size_t)(m0 + r) * 2688 + 768 + (size_t)(pb0[z] + p) * 128 + g * 4] = o;
  }
}

// ---------------------------------------------------------------------------
// Feature build (item_emb pre-converted to bf16): rows 0,1,2,3,5
// one wave per batch row; half-waves split seq entries
// ---------------------------------------------------------------------------
__global__ __launch_bounds__(256)
void k_feat(const int* __restrict__ item_id, const int* __restrict__ likes,
            const int* __restrict__ views, const int* __restrict__ item_seq,
            const unsigned short* __restrict__ iembb, const float* __restrict__ cate_emb,
            unsigned short* __restrict__ xb)
{
  const int b = blockIdx.x * 4 + (threadIdx.x >> 6);
  const int lane = threadIdx.x & 63;
  const int half = lane >> 5, ql = lane & 31;
  const size_t base = (size_t)b * 768;
  const int li = likes[b], vi = views[b], id = item_id[b];

  float4 hs = make_float4(0.f, 0.f, 0.f, 0.f);
  float cnt = 0.f;
  for (int l = half; l < 50; l += 2) {
    int idx = item_seq[b * 50 + l];
    if (idx != 0) {
      cnt += 1.0f;
      ushort4 v = *(const ushort4*)&iembb[(size_t)idx * 128 + ql * 4];
      hs.x += bf2f(v.x); hs.y += bf2f(v.y); hs.z += bf2f(v.z); hs.w += bf2f(v.w);
    }
  }
  cnt  += __shfl_xor(cnt, 32, 64);
  hs.x += __shfl_xor(hs.x, 32, 64);
  hs.y += __shfl_xor(hs.y, 32, 64);
  hs.z += __shfl_xor(hs.z, 32, 64);
  hs.w += __shfl_xor(hs.w, 32, 64);
  const float ic = 1.0f / fmaxf(cnt, 1.0f);

  *(unsigned int*)&xb[base + lane * 2] = 0u;            // row 0 zeros

  {                                                     // rows 1,2 (like/view)
    const float4 v = *(const float4*)&cate_emb[(size_t)(half ? vi : li) * 128 + ql * 4];
    ushort4 o; o.x = f2bf(v.x); o.y = f2bf(v.y); o.z = f2bf(v.z); o.w = f2bf(v.w);
    *(ushort4*)&xb[base + 128 + half * 128 + ql * 4] = o;
  }
  if (half == 0) {                                      // row 3 (id) — direct bf16 copy
    *(ushort4*)&xb[base + 384 + ql * 4] =
        *(const ushort4*)&iembb[(size_t)id * 128 + ql * 4];
  } else {                                              // row 5 (hist mean)
    ushort4 o; o.x = f2bf(hs.x * ic); o.y = f2bf(hs.y * ic);
               o.z = f2bf(hs.z * ic); o.w = f2bf(hs.w * ic);
    *(ushort4*)&xb[base + 640 + ql * 4] = o;
  }
}

// ---------------------------------------------------------------------------
// LayerNorm + exact GELU on y -> xb row 4 (img_feat). one wave per row.
// ---------------------------------------------------------------------------
__global__ __launch_bounds__(256)
void k_ln(const float* __restrict__ y, const float* __restrict__ ln_g,
          const float* __restrict__ ln_b, unsigned short* __restrict__ xb)
{
  const int b = blockIdx.x * 4 + (threadIdx.x >> 6);
  const int lane = threadIdx.x & 63;
  float v0 = y[(size_t)b * 128 + lane], v1 = y[(size_t)b * 128 + lane + 64];
  float s = v0 + v1, s2 = v0 * v0 + v1 * v1;
  #pragma unroll
  for (int o = 32; o > 0; o >>= 1) { s += __shfl_xor(s, o, 64); s2 += __shfl_xor(s2, o, 64); }
  float mu  = s * (1.0f / 128.0f);
  float var = s2 * (1.0f / 128.0f) - mu * mu;
  float rs  = rsqrtf(var + 1e-5f);
  float t0 = (v0 - mu) * rs * ln_g[lane]      + ln_b[lane];
  float t1 = (v1 - mu) * rs * ln_g[lane + 64] + ln_b[lane + 64];
  xb[(size_t)b * 768 + 512 + lane]      = f2bf(gelu_exact(t0));
  xb[(size_t)b * 768 + 512 + lane + 64] = f2bf(gelu_exact(t1));
}

// ---------------------------------------------------------------------------
// GAT attention + residual ELU + SE gate.  one wave per batch row.
// lane owns column pair (2l, 2l+1): float2 LDS reads, packed uint stores.
// ---------------------------------------------------------------------------
__global__ __launch_bounds__(256)
void k_att(const unsigned short* __restrict__ hp, const unsigned short* __restrict__ xb,
           const float* __restrict__ gnn_a, const float* __restrict__ se_w1,
           const float* __restrict__ se_b1, const float* __restrict__ se_w2,
           const float* __restrict__ se_b2, unsigned short* __restrict__ c,
           unsigned short* __restrict__ sb)
{
  __shared__ float hps[4][6][128];
  __shared__ float eis[4][4][6], ejs[4][4][6];
  __shared__ float atts[4][4][6][6];
  const int wv = threadIdx.x >> 6, lane = threadIdx.x & 63;
  const int b = blockIdx.x * 4 + wv;

  #pragma unroll
  for (int n = 0; n < 6; n++) {
    unsigned int pk = *(const unsigned int*)&hp[((size_t)b * 6 + n) * 128 + lane * 2];
    float2 f; f.x = bf2f((unsigned short)(pk & 0xFFFFu));
              f.y = bf2f((unsigned short)(pk >> 16));
    *(float2*)&hps[wv][n][lane * 2] = f;
  }
  __syncthreads();

  if (lane < 24) {                      // (h,n) pairs: ei/ej dots over HD=32
    int h = lane & 3, n = lane >> 2;
    float e1 = 0.f, e2 = 0.f;
    for (int o = 0; o < 32; o++) {
      float v = hps[wv][n][h * 32 + o];
      e1 += v * gnn_a[h * 64 + o];
      e2 += v * gnn_a[h * 64 + 32 + o];
    }
    eis[wv][h][n] = e1; ejs[wv][h][n] = e2;
  }
  __syncthreads();

  if (lane < 24) {                      // per (h,i): leaky + softmax over j
    int h = lane & 3, i = lane >> 2;
    float ev[6]; float mx = -1e30f;
    #pragma unroll
    for (int j = 0; j < 6; j++) {
      float e = eis[wv][h][i] + ejs[wv][h][j];
      e = e > 0.f ? e : 0.2f * e;
      ev[j] = e; mx = fmaxf(mx, e);
    }
    float ssum = 0.f;
    #pragma unroll
    for (int j = 0; j < 6; j++) { ev[j] = expf(ev[j] - mx); ssum += ev[j]; }
    float inv = 1.0f / ssum;
    #pragma unroll
    for (int j = 0; j < 6; j++) atts[wv][h][i][j] = ev[j] * inv;
  }
  __syncthreads();

  const int h = lane >> 4;              // head of col pair (2l, 2l+1)
  float g0[6], g1[6], zz[6];
  #pragma unroll
  for (int n = 0; n < 6; n++) {
    float hn0 = 0.f, hn1 = 0.f;
    #pragma unroll
    for (int m = 0; m < 6; m++) {
      float a = atts[wv][h][n][m];
      float2 v = *(const float2*)&hps[wv][m][lane * 2];
      hn0 += a * v.x; hn1 += a * v.y;
    }
    unsigned int xp = *(const unsigned int*)&xb[(size_t)b * 768 + n * 128 + lane * 2];
    float a0 = hn0 + bf2f((unsigned short)(xp & 0xFFFFu));
    float a1 = hn1 + bf2f((unsigned short)(xp >> 16));
    a0 = a0 > 0.f ? a0 : expm1f(a0);
    a1 = a1 > 0.f ? a1 : expm1f(a1);
    g0[n] = a0; g1[n] = a1;
    float zacc = a0 + a1;
    #pragma unroll
    for (int o = 32; o > 0; o >>= 1) zacc += __shfl_xor(zacc, o, 64);
    zz[n] = zacc * (1.0f / 128.0f);
  }

  // SE gate (tiny 6->3->6 MLP, redundant per lane)
  float rr[3];
  #pragma unroll
  for (int j = 0; j < 3; j++) {
    float a = se_b1[j];
    #pragma unroll
    for (int n = 0; n < 6; n++) a += zz[n] * se_w1[n * 3 + j];
    rr[j] = fmaxf(a, 0.f);
  }
  float wse[6];
  #pragma unroll
  for (int n = 0; n < 6; n++) {
    float a = se_b2[n];
    #pragma unroll
    for (int j = 0; j < 3; j++) a += rr[j] * se_w2[j * 6 + n];
    wse[n] = 1.0f / (1.0f + expf(-a));
  }

  #pragma unroll
  for (int n = 0; n < 6; n++) {
    unsigned int pc = (unsigned int)f2bf(g0[n]) | ((unsigned int)f2bf(g1[n]) << 16);
    unsigned int ps = (unsigned int)f2bf(g0[n] * wse[n]) | ((unsigned int)f2bf(g1[n] * wse[n]) << 16);
    *(unsigned int*)&c[(size_t)b * 2688 + n * 128 + lane * 2]  = pc;
    *(unsigned int*)&sb[(size_t)b * 768 + n * 128 + lane * 2]  = ps;
  }
}

// ---------------------------------------------------------------------------
// Final 256-dot + sigmoid (h2 bf16). one wave per row.
// ---------------------------------------------------------------------------
__global__ __launch_bounds__(256)
void k_out(const unsigned short* __restrict__ h2, const float* __restrict__ w3,
           const float* __restrict__ b3, float* __restrict__ out)
{
  const int b = blockIdx.x * 4 + (threadIdx.x >> 6);
  const int lane = threadIdx.x & 63;
  ushort4 v = *(const ushort4*)&h2[(size_t)b * 256 + lane * 4];
  float a = bf2f(v.x) * w3[lane * 4]     + bf2f(v.y) * w3[lane * 4 + 1]
          + bf2f(v.z) * w3[lane * 4 + 2] + bf2f(v.w) * w3[lane * 4 + 3];
  #pragma unroll
  for (int o = 32; o > 0; o >>= 1) a += __shfl_xor(a, o, 64);
  if (lane == 0) out[b] = 1.0f / (1.0f + expf(-(a + b3[0])));
}

// ---------------------------------------------------------------------------
// Workspace layout (bytes). Aliases: y=sb region, h1=xb region. Peak ~203 MB
// (harness grants >= 213 MB per R1).
// ---------------------------------------------------------------------------
#define OFF_MMWT   0ull           // 32768
#define OFF_WALLT  32768ull       // 32768
#define OFF_BIWT   65536ull       // 163840
#define OFF_W1T    229376ull      // 2752512
#define OFF_W2T    2981888ull     // 262144
#define OFF_IMMB   3244032ull     // 4194304
#define OFF_XB     7438336ull     // 25165824  (alias: h1 16777216 later)
#define OFF_HP     32604160ull    // 25165824  (bf16)
#define OFF_SB     57769984ull    // 25165824  (alias: y 8388608 earlier)
#define OFF_C      82935808ull    // 88080384
#define OFF_H2     171016192ull   // 8388608
#define OFF_IEMB   179404800ull   // 23479808 -> total 202884608

extern "C" void kernel_launch(void* const* d_in, const int* in_sizes, int n_in,
                              void* d_out, int out_size, void* d_ws, size_t ws_size,
                              hipStream_t stream)
{
  const int*   item_id  = (const int*)  d_in[0];
  const float* item_mm  = (const float*)d_in[1];
  const int*   likes    = (const int*)  d_in[2];
  const int*   views    = (const int*)  d_in[3];
  const int*   item_seq = (const int*)  d_in[4];
  const float* item_emb = (const float*)d_in[5];
  const float* cate_emb = (const float*)d_in[6];
  const float* mm_w     = (const float*)d_in[7];
  const float* mm_b     = (const float*)d_in[8];
  const float* ln_g     = (const float*)d_in[9];
  const float* ln_b     = (const float*)d_in[10];
  const float* gnn_W    = (const float*)d_in[11];
  const float* gnn_a    = (const float*)d_in[12];
  const float* se_w1    = (const float*)d_in[13];
  const float* se_b1    = (const float*)d_in[14];
  const float* se_w2    = (const float*)d_in[15];
  const float* se_b2    = (const float*)d_in[16];
  const float* bi_W     = (const float*)d_in[17];
  const float* mlp_w1   = (const float*)d_in[18];
  const float* mlp_b1   = (const float*)d_in[19];
  const float* bn1_g    = (const float*)d_in[20];
  const float* bn1_b    = (const float*)d_in[21];
  const float* mlp_w2   = (const float*)d_in[22];
  const float* mlp_b2   = (const float*)d_in[23];
  const float* bn2_g    = (const float*)d_in[24];
  const float* bn2_b    = (const float*)d_in[25];
  const float* mlp_w3   = (const float*)d_in[26];
  const float* mlp_b3   = (const float*)d_in[27];
  float* out = (float*)d_out;

  char* ws = (char*)d_ws;
  unsigned short* mmwt  = (unsigned short*)(ws + OFF_MMWT);
  unsigned short* wallt = (unsigned short*)(ws + OFF_WALLT);
  unsigned short* biwt  = (unsigned short*)(ws + OFF_BIWT);
  unsigned short* w1t   = (unsigned short*)(ws + OFF_W1T);
  unsigned short* w2t   = (unsigned short*)(ws + OFF_W2T);
  unsigned short* immb  = (unsigned short*)(ws + OFF_IMMB);
  unsigned short* xb    = (unsigned short*)(ws + OFF_XB);
  unsigned short* hpb   = (unsigned short*)(ws + OFF_HP);
  unsigned short* sbb   = (unsigned short*)(ws + OFF_SB);
  float*          yb    = (float*)         (ws + OFF_SB);   // alias: dead before sb
  unsigned short* cbuf  = (unsigned short*)(ws + OFF_C);
  unsigned short* h1b   = (unsigned short*)(ws + OFF_XB);   // alias: xb dead
  unsigned short* h2b   = (unsigned short*)(ws + OFF_H2);
  unsigned short* iembb = (unsigned short*)(ws + OFF_IEMB);

  // 1. small packs + item_emb bf16 convert
  k_pack<<<2048, 256, 0, stream>>>(mm_w, gnn_W, bi_W, item_mm, mmwt, wallt, biwt, immb);
  k_cvt<<<(2934976 + 255) / 256, 256, 0, stream>>>(item_emb, iembb, 2934976);
  // 2-3. coalesced transposes of mlp_w1, mlp_w2
  k_transp<<<dim3(8, 42), 256, 0, stream>>>(mlp_w1, w1t, 2688, 512);
  k_transp<<<dim3(4, 8),  256, 0, stream>>>(mlp_w2, w2t, 512, 256);
  // 4. feature rows 0,1,2,3,5
  k_feat<<<BB / 4, 256, 0, stream>>>(item_id, likes, views, item_seq, iembb, cate_emb, xb);
  // 5. y = item_mm @ mm_w + mm_b
  gemm_bt<0, false><<<dim3(1, 128, 1), 256, 0, stream>>>(immb, 128, mmwt, 128,
      yb, 128, 128, mm_b, nullptr, nullptr);
  // 6. LN + GELU -> xb row 4
  k_ln<<<BB / 4, 256, 0, stream>>>(yb, ln_g, ln_b, xb);
  // 7. hp = x2d @ W_all (bf16 out)
  gemm_bt<2, false><<<dim3(1, 768, 1), 256, 0, stream>>>(xb, 128, wallt, 128,
      hpb, 128, 128, nullptr, nullptr, nullptr);
  // 8. attention + SE -> c[:, :768], sb
  k_att<<<BB / 4, 256, 0, stream>>>(hpb, xb, gnn_a, se_w1, se_b1, se_w2, se_b2, cbuf, sbb);
  // 9. vid GEMM + LDS-transposed pairs -> c[:, 768:]
  gemm_vid<<<dim3(1, 128, 5), 256, 0, stream>>>(sbb, biwt, cbuf);
  // 10. h1 = gelu(bn1(c @ w1 + b1))
  gemm_bt<3, true><<<dim3(4, 128, 1), 256, 0, stream>>>(cbuf, 2688, w1t, 2688,
      h1b, 512, 2688, mlp_b1, bn1_g, bn1_b);
  // 11. h2 = gelu(bn2(h1 @ w2 + b2))
  gemm_bt<3, true><<<dim3(2, 128, 1), 256, 0, stream>>>(h1b, 512, w2t, 512,
      h2b, 256, 512, mlp_b2, bn2_g, bn2_b);
  // 12. out = sigmoid(h2 @ w3 + b3)
  k_out<<<BB / 4, 256, 0, stream>>>(h2b, mlp_w3, mlp_b3, out);
}

// Round 4
// 367.331 us; speedup vs baseline: 1.2848x; 1.0656x over previous
//
#include <hip/hip_runtime.h>
#include <hip/hip_bf16.h>
#include <cstdint>
#include <cstddef>

#define BB 16384

typedef float  floatx4 __attribute__((ext_vector_type(4)));
typedef __bf16 bf16x8  __attribute__((ext_vector_type(8)));

__device__ __forceinline__ unsigned short f2bf(float f) {
  union { float f; unsigned int u; } v; v.f = f;
  unsigned int r = v.u + 0x7FFFu + ((v.u >> 16) & 1u);
  return (unsigned short)(r >> 16);
}
__device__ __forceinline__ float bf2f(unsigned short h) {
  union { unsigned int u; float f; } v; v.u = ((unsigned int)h) << 16;
  return v.f;
}
__device__ __forceinline__ float gelu_exact(float x) {
  return 0.5f * x * (1.0f + erff(x * 0.7071067811865475f));
}

// async global->LDS, 16B per lane; LDS dest = wave-uniform base + lane*16
#define ALOAD16(g, l) \
  __builtin_amdgcn_global_load_lds((const __attribute__((address_space(1))) void*)(g), \
                                   (__attribute__((address_space(3))) void*)(l), 16, 0, 0)

// ---------------------------------------------------------------------------
// Small packs: mm_w^T, gnn_W flat^T, bi_W^T, item_mm bf16
// ---------------------------------------------------------------------------
__global__ void k_pack(const float* __restrict__ mm_w, const float* __restrict__ gnn_W,
                       const float* __restrict__ bi_W, const float* __restrict__ item_mm,
                       unsigned short* __restrict__ mmwt, unsigned short* __restrict__ wallt,
                       unsigned short* __restrict__ biwt, unsigned short* __restrict__ immb)
{
  const int total = 2211840;
  for (int id = blockIdx.x * 256 + threadIdx.x; id < total; id += gridDim.x * 256) {
    if (id < 16384) {                 // mmwt[n][k]
      int n = id / 128, k = id % 128;
      mmwt[id] = f2bf(mm_w[k * 128 + n]);
    } else if (id < 32768) {          // wallt[h*32+o][k]
      int l = id - 16384; int nc = l / 128, k = l % 128;
      wallt[l] = f2bf(gnn_W[(nc >> 5) * 4096 + k * 32 + (nc & 31)]);
    } else if (id < 114688) {         // biwt[f][e][d] <- bi_W[f][d][e]
      int l = id - 32768; int f = l / 16384, rr = l % 16384, e = rr / 128, d = rr % 128;
      biwt[l] = f2bf(bi_W[f * 16384 + d * 128 + e]);
    } else {                          // immb bf16 copy
      int l = id - 114688;
      immb[l] = f2bf(item_mm[l]);
    }
  }
}

// fp32 -> bf16 bulk convert (float4/ushort4), n4 = elems/4
__global__ __launch_bounds__(256)
void k_cvt(const float* __restrict__ in, unsigned short* __restrict__ out, int n4)
{
  int i = blockIdx.x * 256 + threadIdx.x;
  if (i < n4) {
    float4 v = ((const float4*)in)[i];
    ushort4 o; o.x = f2bf(v.x); o.y = f2bf(v.y); o.z = f2bf(v.z); o.w = f2bf(v.w);
    ((ushort4*)out)[i] = o;
  }
}

// ---------------------------------------------------------------------------
// LDS-tiled transpose: in R x C fp32 -> out C x R bf16.  grid(C/64, R/64), 256 thr
// ---------------------------------------------------------------------------
__global__ __launch_bounds__(256)
void k_transp(const float* __restrict__ in, unsigned short* __restrict__ out, int R, int C)
{
  __shared__ float tile[64][65];
  const int c0 = blockIdx.x * 64, r0 = blockIdx.y * 64;
  const int lr = threadIdx.x >> 6;     // 0..3
  const int lc = threadIdx.x & 63;
  #pragma unroll
  for (int i = 0; i < 16; i++) {
    int r = lr + i * 4;
    tile[r][lc] = in[(size_t)(r0 + r) * C + c0 + lc];
  }
  __syncthreads();
  #pragma unroll
  for (int i = 0; i < 16; i++) {
    int c = lr + i * 4;
    out[(size_t)(c0 + c) * R + r0 + lc] = f2bf(tile[lc][c]);
  }
}

// ---------------------------------------------------------------------------
// bf16 MFMA GEMM: C[M,N] = A[M,K] * Bt[N,K]^T.  128x128 tile, BK=64,
// global_load_lds(16B) staging with XOR-8 chunk swizzle (conflict-minimal
// ds_read_b128 under the linear lane->slot constraint of global_load_lds).
// K must be a multiple of 64.
// EPI: 0 = +bias -> f32 | 2 = bf16 | 3 = bias+bn+gelu -> bf16
// ---------------------------------------------------------------------------
template<int EPI, bool SWZ>
__global__ __launch_bounds__(256)
void gemm_bt(const unsigned short* __restrict__ A, int lda,
             const unsigned short* __restrict__ Bt, int ldb,
             void* __restrict__ Cp, int ldc, int K,
             const float* __restrict__ bias, const float* __restrict__ bng,
             const float* __restrict__ bnb)
{
  int bx = blockIdx.x, by = blockIdx.y;
  if constexpr (SWZ) {
    int p = by * gridDim.x + bx;
    int xcd = p & 7, slot = p >> 3;
    bx = slot % gridDim.x;
    by = xcd * (gridDim.y >> 3) + slot / gridDim.x;
  }
  const int n0 = bx * 128;
  const int m0 = by * 128;
  __shared__ __align__(16) unsigned short As[128 * 64];
  __shared__ __align__(16) unsigned short Bs[128 * 64];
  const int t = threadIdx.x;
  const int lane = t & 63, w = t >> 6;
  const int wm = w & 1, wn = w >> 1;
  const int lr = lane & 15, lq = lane >> 4;

  floatx4 acc[4][4];
  #pragma unroll
  for (int a = 0; a < 4; a++)
    #pragma unroll
    for (int b = 0; b < 4; b++) acc[a][b] = (floatx4){0.f, 0.f, 0.f, 0.f};

  // staging: wave w covers rows w*32..+31; issue q covers 8 rows.
  // lane -> (row_in_issue = lane>>3, physical chunk = lane&7); global source
  // chunk is swizzled so physical slot (r, pc) holds logical chunk pc^(r&7).
  const int srow = lane >> 3;
  const int schk = (lane & 7) ^ srow;
  const unsigned short* Ag = A + (size_t)(m0 + w * 32 + srow) * lda + schk * 8;
  const unsigned short* Bg = Bt + (size_t)(n0 + w * 32 + srow) * ldb + schk * 8;
  unsigned short* AsW = As + w * 32 * 64;
  unsigned short* BsW = Bs + w * 32 * 64;

  for (int k0 = 0; k0 < K; k0 += 64) {
    __syncthreads();
    #pragma unroll
    for (int q = 0; q < 4; q++) {
      ALOAD16(Ag + k0 + (size_t)(q * 8) * lda, AsW + q * 512);
      ALOAD16(Bg + k0 + (size_t)(q * 8) * ldb, BsW + q * 512);
    }
    __syncthreads();
    #pragma unroll
    for (int ko = 0; ko < 2; ko++) {
      bf16x8 af[4], bfv[4];
      #pragma unroll
      for (int mt = 0; mt < 4; mt++) {
        const int row = wm * 64 + mt * 16 + lr;
        const int pc = (ko * 4 + lq) ^ (lr & 7);
        af[mt] = __builtin_bit_cast(bf16x8, *(const uint4*)&As[row * 64 + pc * 8]);
      }
      #pragma unroll
      for (int nt = 0; nt < 4; nt++) {
        const int row = wn * 64 + nt * 16 + lr;
        const int pc = (ko * 4 + lq) ^ (lr & 7);
        bfv[nt] = __builtin_bit_cast(bf16x8, *(const uint4*)&Bs[row * 64 + pc * 8]);
      }
      #pragma unroll
      for (int mt = 0; mt < 4; mt++)
        #pragma unroll
        for (int nt = 0; nt < 4; nt++)
          acc[mt][nt] = __builtin_amdgcn_mfma_f32_16x16x32_bf16(af[mt], bfv[nt], acc[mt][nt], 0, 0, 0);
    }
  }

  #pragma unroll
  for (int mt = 0; mt < 4; mt++)
    #pragma unroll
    for (int nt = 0; nt < 4; nt++)
      #pragma unroll
      for (int i = 0; i < 4; i++) {
        const int cm = m0 + wm * 64 + mt * 16 + lq * 4 + i;   // row = quad*4+reg
        const int cn = n0 + wn * 64 + nt * 16 + lr;           // col = lane&15
        float v = acc[mt][nt][i];
        size_t idx = (size_t)cm * ldc + cn;
        if constexpr (EPI == 0) {
          ((float*)Cp)[idx] = v + bias[cn];
        } else if constexpr (EPI == 2) {
          ((unsigned short*)Cp)[idx] = f2bf(v);
        } else {
          float tt = v + bias[cn];
          tt = tt * (bng[cn] * 0.9999950000374997f) + bnb[cn];  // g/sqrt(1+1e-5)
          ((unsigned short*)Cp)[idx] = f2bf(gelu_exact(tt));
        }
      }
}

// ---------------------------------------------------------------------------
// vid GEMM + pairs, LDS-transposed epilogue.  BK=64 + swizzle (K=128).
// grid(1, 128, 5): z = feature i, m0 = by*128 batch rows.
// ---------------------------------------------------------------------------
__global__ __launch_bounds__(256)
void gemm_vid(const unsigned short* __restrict__ sbb, const unsigned short* __restrict__ biwt,
              unsigned short* __restrict__ c)
{
  const int z = blockIdx.z;
  const int m0 = blockIdx.y * 128;
  // LDS: staging 2x8 KB reused as vid tile (128 x pad130 bf16 = 33.3 KB)
  __shared__ __align__(16) unsigned short smem[128 * 130];
  unsigned short* As = smem;            // 128*64
  unsigned short* Bs = smem + 8192;     // 128*64
  const int t = threadIdx.x;
  const int lane = t & 63, w = t >> 6;
  const int wm = w & 1, wn = w >> 1;
  const int lr = lane & 15, lq = lane >> 4;

  floatx4 acc[4][4];
  #pragma unroll
  for (int a = 0; a < 4; a++)
    #pragma unroll
    for (int b = 0; b < 4; b++) acc[a][b] = (floatx4){0.f, 0.f, 0.f, 0.f};

  const int srow = lane >> 3;
  const int schk = (lane & 7) ^ srow;
  const unsigned short* Ag = sbb + (size_t)(m0 + w * 32 + srow) * 768 + z * 128 + schk * 8;
  const unsigned short* Bg = biwt + z * 16384 + (size_t)(w * 32 + srow) * 128 + schk * 8;
  unsigned short* AsW = As + w * 32 * 64;
  unsigned short* BsW = Bs + w * 32 * 64;

  for (int k0 = 0; k0 < 128; k0 += 64) {
    __syncthreads();
    #pragma unroll
    for (int q = 0; q < 4; q++) {
      ALOAD16(Ag + k0 + (size_t)(q * 8) * 768, AsW + q * 512);
      ALOAD16(Bg + k0 + (size_t)(q * 8) * 128, BsW + q * 512);
    }
    __syncthreads();
    #pragma unroll
    for (int ko = 0; ko < 2; ko++) {
      bf16x8 af[4], bfv[4];
      #pragma unroll
      for (int mt = 0; mt < 4; mt++) {
        const int row = wm * 64 + mt * 16 + lr;
        const int pc = (ko * 4 + lq) ^ (lr & 7);
        af[mt] = __builtin_bit_cast(bf16x8, *(const uint4*)&As[row * 64 + pc * 8]);
      }
      #pragma unroll
      for (int nt = 0; nt < 4; nt++) {
        const int row = wn * 64 + nt * 16 + lr;
        const int pc = (ko * 4 + lq) ^ (lr & 7);
        bfv[nt] = __builtin_bit_cast(bf16x8, *(const uint4*)&Bs[row * 64 + pc * 8]);
      }
      #pragma unroll
      for (int mt = 0; mt < 4; mt++)
        #pragma unroll
        for (int nt = 0; nt < 4; nt++)
          acc[mt][nt] = __builtin_amdgcn_mfma_f32_16x16x32_bf16(af[mt], bfv[nt], acc[mt][nt], 0, 0, 0);
    }
  }

  __syncthreads();                      // staging dead; reuse smem as vid tile
  #pragma unroll
  for (int mt = 0; mt < 4; mt++)
    #pragma unroll
    for (int nt = 0; nt < 4; nt++)
      #pragma unroll
      for (int i = 0; i < 4; i++) {
        const int rr = wm * 64 + mt * 16 + lq * 4 + i;
        const int cc = wn * 64 + nt * 16 + lr;
        smem[rr * 130 + cc] = f2bf(acc[mt][nt][i]);
      }
  __syncthreads();

  const int pb0[5] = {0, 5, 9, 12, 14};
  const int npairs = 5 - z;
  const int tot = 128 * 32 * npairs;    // ushort4 units
  for (int e = t; e < tot; e += 256) {
    const int g  = e & 31;
    const int rp = e >> 5;
    const int p  = rp % npairs;
    const int r  = rp / npairs;
    ushort4 vv = *(const ushort4*)&smem[r * 130 + g * 4];
    ushort4 sv = *(const ushort4*)&sbb[(size_t)(m0 + r) * 768 + (z + 1 + p) * 128 + g * 4];
    ushort4 o;
    o.x = f2bf(bf2f(vv.x) * bf2f(sv.x));
    o.y = f2bf(bf2f(vv.y) * bf2f(sv.y));
    o.z = f2bf(bf2f(vv.z) * bf2f(sv.z));
    o.w = f2bf(bf2f(vv.w) * bf2f(sv.w));
    *(ushort4*)&c[(size_t)(m0 + r) * 2688 + 768 + (size_t)(pb0[z] + p) * 128 + g * 4] = o;
  }
}

// ---------------------------------------------------------------------------
// Feature build: rows 0,1,2,3,5.  one wave per row; half-waves split seq.
// All 25 indices prefetched to registers so the 25 gathers issue independently.
// ---------------------------------------------------------------------------
__global__ __launch_bounds__(256)
void k_feat(const int* __restrict__ item_id, const int* __restrict__ likes,
            const int* __restrict__ views, const int* __restrict__ item_seq,
            const unsigned short* __restrict__ iembb, const float* __restrict__ cate_emb,
            unsigned short* __restrict__ xb)
{
  const int b = blockIdx.x * 4 + (threadIdx.x >> 6);
  const int lane = threadIdx.x & 63;
  const int half = lane >> 5, ql = lane & 31;
  const size_t base = (size_t)b * 768;
  const int li = likes[b], vi = views[b], id = item_id[b];

  int idxs[25];
  #pragma unroll
  for (int j = 0; j < 25; j++) idxs[j] = item_seq[b * 50 + half + 2 * j];

  float4 hs = make_float4(0.f, 0.f, 0.f, 0.f);
  float cnt = 0.f;
  #pragma unroll
  for (int j = 0; j < 25; j++) {
    const int idx = idxs[j];
    if (idx != 0) {
      cnt += 1.0f;
      ushort4 v = *(const ushort4*)&iembb[(size_t)idx * 128 + ql * 4];
      hs.x += bf2f(v.x); hs.y += bf2f(v.y); hs.z += bf2f(v.z); hs.w += bf2f(v.w);
    }
  }
  cnt  += __shfl_xor(cnt, 32, 64);
  hs.x += __shfl_xor(hs.x, 32, 64);
  hs.y += __shfl_xor(hs.y, 32, 64);
  hs.z += __shfl_xor(hs.z, 32, 64);
  hs.w += __shfl_xor(hs.w, 32, 64);
  const float ic = 1.0f / fmaxf(cnt, 1.0f);

  *(unsigned int*)&xb[base + lane * 2] = 0u;            // row 0 zeros

  {                                                     // rows 1,2 (like/view)
    const float4 v = *(const float4*)&cate_emb[(size_t)(half ? vi : li) * 128 + ql * 4];
    ushort4 o; o.x = f2bf(v.x); o.y = f2bf(v.y); o.z = f2bf(v.z); o.w = f2bf(v.w);
    *(ushort4*)&xb[base + 128 + half * 128 + ql * 4] = o;
  }
  if (half == 0) {                                      // row 3 (id) — direct bf16 copy
    *(ushort4*)&xb[base + 384 + ql * 4] =
        *(const ushort4*)&iembb[(size_t)id * 128 + ql * 4];
  } else {                                              // row 5 (hist mean)
    ushort4 o; o.x = f2bf(hs.x * ic); o.y = f2bf(hs.y * ic);
               o.z = f2bf(hs.z * ic); o.w = f2bf(hs.w * ic);
    *(ushort4*)&xb[base + 640 + ql * 4] = o;
  }
}

// ---------------------------------------------------------------------------
// LayerNorm + exact GELU on y -> xb row 4 (img_feat). one wave per row.
// ---------------------------------------------------------------------------
__global__ __launch_bounds__(256)
void k_ln(const float* __restrict__ y, const float* __restrict__ ln_g,
          const float* __restrict__ ln_b, unsigned short* __restrict__ xb)
{
  const int b = blockIdx.x * 4 + (threadIdx.x >> 6);
  const int lane = threadIdx.x & 63;
  float v0 = y[(size_t)b * 128 + lane], v1 = y[(size_t)b * 128 + lane + 64];
  float s = v0 + v1, s2 = v0 * v0 + v1 * v1;
  #pragma unroll
  for (int o = 32; o > 0; o >>= 1) { s += __shfl_xor(s, o, 64); s2 += __shfl_xor(s2, o, 64); }
  float mu  = s * (1.0f / 128.0f);
  float var = s2 * (1.0f / 128.0f) - mu * mu;
  float rs  = rsqrtf(var + 1e-5f);
  float t0 = (v0 - mu) * rs * ln_g[lane]      + ln_b[lane];
  float t1 = (v1 - mu) * rs * ln_g[lane + 64] + ln_b[lane + 64];
  xb[(size_t)b * 768 + 512 + lane]      = f2bf(gelu_exact(t0));
  xb[(size_t)b * 768 + 512 + lane + 64] = f2bf(gelu_exact(t1));
}

// ---------------------------------------------------------------------------
// GAT attention + residual ELU + SE gate.  one wave per batch row.
// ---------------------------------------------------------------------------
__global__ __launch_bounds__(256)
void k_att(const unsigned short* __restrict__ hp, const unsigned short* __restrict__ xb,
           const float* __restrict__ gnn_a, const float* __restrict__ se_w1,
           const float* __restrict__ se_b1, const float* __restrict__ se_w2,
           const float* __restrict__ se_b2, unsigned short* __restrict__ c,
           unsigned short* __restrict__ sb)
{
  __shared__ float hps[4][6][128];
  __shared__ float eis[4][4][6], ejs[4][4][6];
  __shared__ float atts[4][4][6][6];
  const int wv = threadIdx.x >> 6, lane = threadIdx.x & 63;
  const int b = blockIdx.x * 4 + wv;

  #pragma unroll
  for (int n = 0; n < 6; n++) {
    unsigned int pk = *(const unsigned int*)&hp[((size_t)b * 6 + n) * 128 + lane * 2];
    float2 f; f.x = bf2f((unsigned short)(pk & 0xFFFFu));
              f.y = bf2f((unsigned short)(pk >> 16));
    *(float2*)&hps[wv][n][lane * 2] = f;
  }
  __syncthreads();

  if (lane < 24) {                      // (h,n) pairs: ei/ej dots over HD=32
    int h = lane & 3, n = lane >> 2;
    float e1 = 0.f, e2 = 0.f;
    for (int o = 0; o < 32; o++) {
      float v = hps[wv][n][h * 32 + o];
      e1 += v * gnn_a[h * 64 + o];
      e2 += v * gnn_a[h * 64 + 32 + o];
    }
    eis[wv][h][n] = e1; ejs[wv][h][n] = e2;
  }
  __syncthreads();

  if (lane < 24) {                      // per (h,i): leaky + softmax over j
    int h = lane & 3, i = lane >> 2;
    float ev[6]; float mx = -1e30f;
    #pragma unroll
    for (int j = 0; j < 6; j++) {
      float e = eis[wv][h][i] + ejs[wv][h][j];
      e = e > 0.f ? e : 0.2f * e;
      ev[j] = e; mx = fmaxf(mx, e);
    }
    float ssum = 0.f;
    #pragma unroll
    for (int j = 0; j < 6; j++) { ev[j] = expf(ev[j] - mx); ssum += ev[j]; }
    float inv = 1.0f / ssum;
    #pragma unroll
    for (int j = 0; j < 6; j++) atts[wv][h][i][j] = ev[j] * inv;
  }
  __syncthreads();

  const int h = lane >> 4;              // head of col pair (2l, 2l+1)
  float g0[6], g1[6], zz[6];
  #pragma unroll
  for (int n = 0; n < 6; n++) {
    float hn0 = 0.f, hn1 = 0.f;
    #pragma unroll
    for (int m = 0; m < 6; m++) {
      float a = atts[wv][h][n][m];
      float2 v = *(const float2*)&hps[wv][m][lane * 2];
      hn0 += a * v.x; hn1 += a * v.y;
    }
    unsigned int xp = *(const unsigned int*)&xb[(size_t)b * 768 + n * 128 + lane * 2];
    float a0 = hn0 + bf2f((unsigned short)(xp & 0xFFFFu));
    float a1 = hn1 + bf2f((unsigned short)(xp >> 16));
    a0 = a0 > 0.f ? a0 : expm1f(a0);
    a1 = a1 > 0.f ? a1 : expm1f(a1);
    g0[n] = a0; g1[n] = a1;
    float zacc = a0 + a1;
    #pragma unroll
    for (int o = 32; o > 0; o >>= 1) zacc += __shfl_xor(zacc, o, 64);
    zz[n] = zacc * (1.0f / 128.0f);
  }

  // SE gate (tiny 6->3->6 MLP, redundant per lane)
  float rr[3];
  #pragma unroll
  for (int j = 0; j < 3; j++) {
    float a = se_b1[j];
    #pragma unroll
    for (int n = 0; n < 6; n++) a += zz[n] * se_w1[n * 3 + j];
    rr[j] = fmaxf(a, 0.f);
  }
  float wse[6];
  #pragma unroll
  for (int n = 0; n < 6; n++) {
    float a = se_b2[n];
    #pragma unroll
    for (int j = 0; j < 3; j++) a += rr[j] * se_w2[j * 6 + n];
    wse[n] = 1.0f / (1.0f + expf(-a));
  }

  #pragma unroll
  for (int n = 0; n < 6; n++) {
    unsigned int pc = (unsigned int)f2bf(g0[n]) | ((unsigned int)f2bf(g1[n]) << 16);
    unsigned int ps = (unsigned int)f2bf(g0[n] * wse[n]) | ((unsigned int)f2bf(g1[n] * wse[n]) << 16);
    *(unsigned int*)&c[(size_t)b * 2688 + n * 128 + lane * 2]  = pc;
    *(unsigned int*)&sb[(size_t)b * 768 + n * 128 + lane * 2]  = ps;
  }
}

// ---------------------------------------------------------------------------
// Final 256-dot + sigmoid (h2 bf16). one wave per row.
// ---------------------------------------------------------------------------
__global__ __launch_bounds__(256)
void k_out(const unsigned short* __restrict__ h2, const float* __restrict__ w3,
           const float* __restrict__ b3, float* __restrict__ out)
{
  const int b = blockIdx.x * 4 + (threadIdx.x >> 6);
  const int lane = threadIdx.x & 63;
  ushort4 v = *(const ushort4*)&h2[(size_t)b * 256 + lane * 4];
  float a = bf2f(v.x) * w3[lane * 4]     + bf2f(v.y) * w3[lane * 4 + 1]
          + bf2f(v.z) * w3[lane * 4 + 2] + bf2f(v.w) * w3[lane * 4 + 3];
  #pragma unroll
  for (int o = 32; o > 0; o >>= 1) a += __shfl_xor(a, o, 64);
  if (lane == 0) out[b] = 1.0f / (1.0f + expf(-(a + b3[0])));
}

// ---------------------------------------------------------------------------
// Workspace layout (bytes). Aliases: y=sb region, h1=xb region. Peak ~203 MB.
// ---------------------------------------------------------------------------
#define OFF_MMWT   0ull           // 32768
#define OFF_WALLT  32768ull       // 32768
#define OFF_BIWT   65536ull       // 163840
#define OFF_W1T    229376ull      // 2752512
#define OFF_W2T    2981888ull     // 262144
#define OFF_IMMB   3244032ull     // 4194304
#define OFF_XB     7438336ull     // 25165824  (alias: h1 16777216 later)
#define OFF_HP     32604160ull    // 25165824  (bf16)
#define OFF_SB     57769984ull    // 25165824  (alias: y 8388608 earlier)
#define OFF_C      82935808ull    // 88080384
#define OFF_H2     171016192ull   // 8388608
#define OFF_IEMB   179404800ull   // 23479808 -> total 202884608

extern "C" void kernel_launch(void* const* d_in, const int* in_sizes, int n_in,
                              void* d_out, int out_size, void* d_ws, size_t ws_size,
                              hipStream_t stream)
{
  const int*   item_id  = (const int*)  d_in[0];
  const float* item_mm  = (const float*)d_in[1];
  const int*   likes    = (const int*)  d_in[2];
  const int*   views    = (const int*)  d_in[3];
  const int*   item_seq = (const int*)  d_in[4];
  const float* item_emb = (const float*)d_in[5];
  const float* cate_emb = (const float*)d_in[6];
  const float* mm_w     = (const float*)d_in[7];
  const float* mm_b     = (const float*)d_in[8];
  const float* ln_g     = (const float*)d_in[9];
  const float* ln_b     = (const float*)d_in[10];
  const float* gnn_W    = (const float*)d_in[11];
  const float* gnn_a    = (const float*)d_in[12];
  const float* se_w1    = (const float*)d_in[13];
  const float* se_b1    = (const float*)d_in[14];
  const float* se_w2    = (const float*)d_in[15];
  const float* se_b2    = (const float*)d_in[16];
  const float* bi_W     = (const float*)d_in[17];
  const float* mlp_w1   = (const float*)d_in[18];
  const float* mlp_b1   = (const float*)d_in[19];
  const float* bn1_g    = (const float*)d_in[20];
  const float* bn1_b    = (const float*)d_in[21];
  const float* mlp_w2   = (const float*)d_in[22];
  const float* mlp_b2   = (const float*)d_in[23];
  const float* bn2_g    = (const float*)d_in[24];
  const float* bn2_b    = (const float*)d_in[25];
  const float* mlp_w3   = (const float*)d_in[26];
  const float* mlp_b3   = (const float*)d_in[27];
  float* out = (float*)d_out;

  char* ws = (char*)d_ws;
  unsigned short* mmwt  = (unsigned short*)(ws + OFF_MMWT);
  unsigned short* wallt = (unsigned short*)(ws + OFF_WALLT);
  unsigned short* biwt  = (unsigned short*)(ws + OFF_BIWT);
  unsigned short* w1t   = (unsigned short*)(ws + OFF_W1T);
  unsigned short* w2t   = (unsigned short*)(ws + OFF_W2T);
  unsigned short* immb  = (unsigned short*)(ws + OFF_IMMB);
  unsigned short* xb    = (unsigned short*)(ws + OFF_XB);
  unsigned short* hpb   = (unsigned short*)(ws + OFF_HP);
  unsigned short* sbb   = (unsigned short*)(ws + OFF_SB);
  float*          yb    = (float*)         (ws + OFF_SB);   // alias: dead before sb
  unsigned short* cbuf  = (unsigned short*)(ws + OFF_C);
  unsigned short* h1b   = (unsigned short*)(ws + OFF_XB);   // alias: xb dead
  unsigned short* h2b   = (unsigned short*)(ws + OFF_H2);
  unsigned short* iembb = (unsigned short*)(ws + OFF_IEMB);

  // 1. small packs + item_emb bf16 convert
  k_pack<<<2048, 256, 0, stream>>>(mm_w, gnn_W, bi_W, item_mm, mmwt, wallt, biwt, immb);
  k_cvt<<<(2934976 + 255) / 256, 256, 0, stream>>>(item_emb, iembb, 2934976);
  // 2-3. coalesced transposes of mlp_w1, mlp_w2
  k_transp<<<dim3(8, 42), 256, 0, stream>>>(mlp_w1, w1t, 2688, 512);
  k_transp<<<dim3(4, 8),  256, 0, stream>>>(mlp_w2, w2t, 512, 256);
  // 4. feature rows 0,1,2,3,5
  k_feat<<<BB / 4, 256, 0, stream>>>(item_id, likes, views, item_seq, iembb, cate_emb, xb);
  // 5. y = item_mm @ mm_w + mm_b
  gemm_bt<0, false><<<dim3(1, 128, 1), 256, 0, stream>>>(immb, 128, mmwt, 128,
      yb, 128, 128, mm_b, nullptr, nullptr);
  // 6. LN + GELU -> xb row 4
  k_ln<<<BB / 4, 256, 0, stream>>>(yb, ln_g, ln_b, xb);
  // 7. hp = x2d @ W_all (bf16 out)
  gemm_bt<2, false><<<dim3(1, 768, 1), 256, 0, stream>>>(xb, 128, wallt, 128,
      hpb, 128, 128, nullptr, nullptr, nullptr);
  // 8. attention + SE -> c[:, :768], sb
  k_att<<<BB / 4, 256, 0, stream>>>(hpb, xb, gnn_a, se_w1, se_b1, se_w2, se_b2, cbuf, sbb);
  // 9. vid GEMM + LDS-transposed pairs -> c[:, 768:]
  gemm_vid<<<dim3(1, 128, 5), 256, 0, stream>>>(sbb, biwt, cbuf);
  // 10. h1 = gelu(bn1(c @ w1 + b1))
  gemm_bt<3, true><<<dim3(4, 128, 1), 256, 0, stream>>>(cbuf, 2688, w1t, 2688,
      h1b, 512, 2688, mlp_b1, bn1_g, bn1_b);
  // 11. h2 = gelu(bn2(h1 @ w2 + b2))
  gemm_bt<3, true><<<dim3(2, 128, 1), 256, 0, stream>>>(h1b, 512, w2t, 512,
      h2b, 256, 512, mlp_b2, bn2_g, bn2_b);
  // 12. out = sigmoid(h2 @ w3 + b3)
  k_out<<<BB / 4, 256, 0, stream>>>(h2b, mlp_w3, mlp_b3, out);
}

// Round 5
// 349.580 us; speedup vs baseline: 1.3500x; 1.0508x over previous
//
#include <hip/hip_runtime.h>
#include <hip/hip_bf16.h>
#include <cstdint>
#include <cstddef>

#define BB 16384

typedef float  floatx4 __attribute__((ext_vector_type(4)));
typedef __bf16 bf16x8  __attribute__((ext_vector_type(8)));

__device__ __forceinline__ unsigned short f2bf(float f) {
  union { float f; unsigned int u; } v; v.f = f;
  unsigned int r = v.u + 0x7FFFu + ((v.u >> 16) & 1u);
  return (unsigned short)(r >> 16);
}
__device__ __forceinline__ float bf2f(unsigned short h) {
  union { unsigned int u; float f; } v; v.u = ((unsigned int)h) << 16;
  return v.f;
}
__device__ __forceinline__ float gelu_exact(float x) {
  return 0.5f * x * (1.0f + erff(x * 0.7071067811865475f));
}

// async global->LDS, 16B per lane; LDS dest = wave-uniform base + lane*16
#define ALOAD16(g, l) \
  __builtin_amdgcn_global_load_lds((const __attribute__((address_space(1))) void*)(g), \
                                   (__attribute__((address_space(3))) void*)(l), 16, 0, 0)

// ---------------------------------------------------------------------------
// Packs + item_emb bf16 convert (merged): mm_w^T, gnn_W^T, bi_W^T, item_mm,
// item_emb (vec4).
// ---------------------------------------------------------------------------
__global__ void k_pack(const float* __restrict__ mm_w, const float* __restrict__ gnn_W,
                       const float* __restrict__ bi_W, const float* __restrict__ item_mm,
                       const float* __restrict__ item_emb,
                       unsigned short* __restrict__ mmwt, unsigned short* __restrict__ wallt,
                       unsigned short* __restrict__ biwt, unsigned short* __restrict__ immb,
                       unsigned short* __restrict__ iembb)
{
  const int total = 2211840 + 2934976;          // scalar jobs + vec4 cvt jobs
  for (int id = blockIdx.x * 256 + threadIdx.x; id < total; id += gridDim.x * 256) {
    if (id < 16384) {                 // mmwt[n][k]
      int n = id / 128, k = id % 128;
      mmwt[id] = f2bf(mm_w[k * 128 + n]);
    } else if (id < 32768) {          // wallt[h*32+o][k]
      int l = id - 16384; int nc = l / 128, k = l % 128;
      wallt[l] = f2bf(gnn_W[(nc >> 5) * 4096 + k * 32 + (nc & 31)]);
    } else if (id < 114688) {         // biwt[f][e][d] <- bi_W[f][d][e]
      int l = id - 32768; int f = l / 16384, rr = l % 16384, e = rr / 128, d = rr % 128;
      biwt[l] = f2bf(bi_W[f * 16384 + d * 128 + e]);
    } else if (id < 2211840) {        // immb bf16 copy
      int l = id - 114688;
      immb[l] = f2bf(item_mm[l]);
    } else {                          // item_emb cvt, vec4
      int l = id - 2211840;
      float4 v = ((const float4*)item_emb)[l];
      ushort4 o; o.x = f2bf(v.x); o.y = f2bf(v.y); o.z = f2bf(v.z); o.w = f2bf(v.w);
      ((ushort4*)iembb)[l] = o;
    }
  }
}

// ---------------------------------------------------------------------------
// LDS-tiled transpose: in R x C fp32 -> out C x R bf16.  grid(C/64, R/64), 256 thr
// ---------------------------------------------------------------------------
__global__ __launch_bounds__(256)
void k_transp(const float* __restrict__ in, unsigned short* __restrict__ out, int R, int C)
{
  __shared__ float tile[64][65];
  const int c0 = blockIdx.x * 64, r0 = blockIdx.y * 64;
  const int lr = threadIdx.x >> 6;     // 0..3
  const int lc = threadIdx.x & 63;
  #pragma unroll
  for (int i = 0; i < 16; i++) {
    int r = lr + i * 4;
    tile[r][lc] = in[(size_t)(r0 + r) * C + c0 + lc];
  }
  __syncthreads();
  #pragma unroll
  for (int i = 0; i < 16; i++) {
    int c = lr + i * 4;
    out[(size_t)(c0 + c) * R + r0 + lc] = f2bf(tile[lc][c]);
  }
}

// ---------------------------------------------------------------------------
// bf16 MFMA GEMM, 512 threads (8 waves): C[M,N] = A[M,K] * Bt[N,K]^T.
// Tile BM x 128, BK=64, XOR-8 swizzled global_load_lds staging.
// BM=128: waves 2x4, per-wave 64x32.  BM=64: waves 1x8, per-wave 64x16.
// EPI: 0 = +bias -> f32 | 2 = bf16 | 3 = bias+bn+gelu -> bf16
// ---------------------------------------------------------------------------
template<int BM, int EPI, bool SWZ>
__global__ __launch_bounds__(512)
void gemm_bt(const unsigned short* __restrict__ A, int lda,
             const unsigned short* __restrict__ Bt, int ldb,
             void* __restrict__ Cp, int ldc, int K,
             const float* __restrict__ bias, const float* __restrict__ bng,
             const float* __restrict__ bnb)
{
  constexpr int WGM = BM / 64;          // 1 or 2
  constexpr int WGN = 8 / WGM;          // 8 or 4
  constexpr int TN  = 128 / WGN;        // 16 or 32
  constexpr int NT  = TN / 16;          // 1 or 2
  constexpr int NRW = (BM + 128) / 8;   // staged rows per wave (24 or 32)
  constexpr int ISS = NRW / 8;          // ALOAD16 issues per wave (3 or 4)

  int bx = blockIdx.x, by = blockIdx.y;
  if constexpr (SWZ) {
    int p = by * gridDim.x + bx;
    int xcd = p & 7, slot = p >> 3;
    bx = slot % gridDim.x;
    by = xcd * (gridDim.y >> 3) + slot / gridDim.x;
  }
  const int n0 = bx * 128;
  const int m0 = by * BM;
  __shared__ __align__(16) unsigned short As[BM * 64];
  __shared__ __align__(16) unsigned short Bs[128 * 64];
  const int t = threadIdx.x;
  const int lane = t & 63, w = t >> 6;
  const int wm = w % WGM, wn = w / WGM;
  const int lr = lane & 15, lq = lane >> 4;

  floatx4 acc[4][NT];
  #pragma unroll
  for (int a = 0; a < 4; a++)
    #pragma unroll
    for (int b = 0; b < NT; b++) acc[a][b] = (floatx4){0.f, 0.f, 0.f, 0.f};

  // staging: concatenated [A-tile rows 0..BM) ; B-tile rows 0..128). wave w
  // stages rows w*NRW .. w*NRW+NRW.  lane -> (srow = lane>>3, phys chunk =
  // lane&7); source chunk swizzled: slot (r, pc) holds logical chunk pc^(r&7).
  const int srow = lane >> 3;
  const int schk = (lane & 7) ^ srow;
  const int rb0 = w * NRW;

  for (int k0 = 0; k0 < K; k0 += 64) {
    __syncthreads();
    #pragma unroll
    for (int q = 0; q < ISS; q++) {
      const int rb = rb0 + q * 8;
      if (rb < BM) {
        ALOAD16(A + (size_t)(m0 + rb + srow) * lda + k0 + schk * 8, As + rb * 64);
      } else {
        const int rbb = rb - BM;
        ALOAD16(Bt + (size_t)(n0 + rbb + srow) * ldb + k0 + schk * 8, Bs + rbb * 64);
      }
    }
    __syncthreads();
    #pragma unroll
    for (int ko = 0; ko < 2; ko++) {
      bf16x8 af[4], bfv[NT];
      #pragma unroll
      for (int mt = 0; mt < 4; mt++) {
        const int row = wm * 64 + mt * 16 + lr;
        const int pc = (ko * 4 + lq) ^ (lr & 7);
        af[mt] = __builtin_bit_cast(bf16x8, *(const uint4*)&As[row * 64 + pc * 8]);
      }
      #pragma unroll
      for (int nt = 0; nt < NT; nt++) {
        const int row = wn * TN + nt * 16 + lr;
        const int pc = (ko * 4 + lq) ^ (lr & 7);
        bfv[nt] = __builtin_bit_cast(bf16x8, *(const uint4*)&Bs[row * 64 + pc * 8]);
      }
      #pragma unroll
      for (int mt = 0; mt < 4; mt++)
        #pragma unroll
        for (int nt = 0; nt < NT; nt++)
          acc[mt][nt] = __builtin_amdgcn_mfma_f32_16x16x32_bf16(af[mt], bfv[nt], acc[mt][nt], 0, 0, 0);
    }
  }

  #pragma unroll
  for (int mt = 0; mt < 4; mt++)
    #pragma unroll
    for (int nt = 0; nt < NT; nt++)
      #pragma unroll
      for (int i = 0; i < 4; i++) {
        const int cm = m0 + wm * 64 + mt * 16 + lq * 4 + i;   // row = quad*4+reg
        const int cn = n0 + wn * TN + nt * 16 + lr;           // col = lane&15
        float v = acc[mt][nt][i];
        size_t idx = (size_t)cm * ldc + cn;
        if constexpr (EPI == 0) {
          ((float*)Cp)[idx] = v + bias[cn];
        } else if constexpr (EPI == 2) {
          ((unsigned short*)Cp)[idx] = f2bf(v);
        } else {
          float tt = v + bias[cn];
          tt = tt * (bng[cn] * 0.9999950000374997f) + bnb[cn];  // g/sqrt(1+1e-5)
          ((unsigned short*)Cp)[idx] = f2bf(gelu_exact(tt));
        }
      }
}

// ---------------------------------------------------------------------------
// vid GEMM + pairs, LDS-transposed epilogue.  256 thr, BK=64 + swizzle (K=128).
// grid(1, 128, 5): z = feature i, m0 = by*128 batch rows.
// ---------------------------------------------------------------------------
__global__ __launch_bounds__(256)
void gemm_vid(const unsigned short* __restrict__ sbb, const unsigned short* __restrict__ biwt,
              unsigned short* __restrict__ c)
{
  const int z = blockIdx.z;
  const int m0 = blockIdx.y * 128;
  __shared__ __align__(16) unsigned short smem[128 * 130];
  unsigned short* As = smem;            // 128*64
  unsigned short* Bs = smem + 8192;     // 128*64
  const int t = threadIdx.x;
  const int lane = t & 63, w = t >> 6;
  const int wm = w & 1, wn = w >> 1;
  const int lr = lane & 15, lq = lane >> 4;

  floatx4 acc[4][4];
  #pragma unroll
  for (int a = 0; a < 4; a++)
    #pragma unroll
    for (int b = 0; b < 4; b++) acc[a][b] = (floatx4){0.f, 0.f, 0.f, 0.f};

  const int srow = lane >> 3;
  const int schk = (lane & 7) ^ srow;
  const unsigned short* Ag = sbb + (size_t)(m0 + w * 32 + srow) * 768 + z * 128 + schk * 8;
  const unsigned short* Bg = biwt + z * 16384 + (size_t)(w * 32 + srow) * 128 + schk * 8;
  unsigned short* AsW = As + w * 32 * 64;
  unsigned short* BsW = Bs + w * 32 * 64;

  for (int k0 = 0; k0 < 128; k0 += 64) {
    __syncthreads();
    #pragma unroll
    for (int q = 0; q < 4; q++) {
      ALOAD16(Ag + k0 + (size_t)(q * 8) * 768, AsW + q * 512);
      ALOAD16(Bg + k0 + (size_t)(q * 8) * 128, BsW + q * 512);
    }
    __syncthreads();
    #pragma unroll
    for (int ko = 0; ko < 2; ko++) {
      bf16x8 af[4], bfv[4];
      #pragma unroll
      for (int mt = 0; mt < 4; mt++) {
        const int row = wm * 64 + mt * 16 + lr;
        const int pc = (ko * 4 + lq) ^ (lr & 7);
        af[mt] = __builtin_bit_cast(bf16x8, *(const uint4*)&As[row * 64 + pc * 8]);
      }
      #pragma unroll
      for (int nt = 0; nt < 4; nt++) {
        const int row = wn * 64 + nt * 16 + lr;
        const int pc = (ko * 4 + lq) ^ (lr & 7);
        bfv[nt] = __builtin_bit_cast(bf16x8, *(const uint4*)&Bs[row * 64 + pc * 8]);
      }
      #pragma unroll
      for (int mt = 0; mt < 4; mt++)
        #pragma unroll
        for (int nt = 0; nt < 4; nt++)
          acc[mt][nt] = __builtin_amdgcn_mfma_f32_16x16x32_bf16(af[mt], bfv[nt], acc[mt][nt], 0, 0, 0);
    }
  }

  __syncthreads();                      // staging dead; reuse smem as vid tile
  #pragma unroll
  for (int mt = 0; mt < 4; mt++)
    #pragma unroll
    for (int nt = 0; nt < 4; nt++)
      #pragma unroll
      for (int i = 0; i < 4; i++) {
        const int rr = wm * 64 + mt * 16 + lq * 4 + i;
        const int cc = wn * 64 + nt * 16 + lr;
        smem[rr * 130 + cc] = f2bf(acc[mt][nt][i]);
      }
  __syncthreads();

  const int pb0[5] = {0, 5, 9, 12, 14};
  const int npairs = 5 - z;
  const int tot = 128 * 32 * npairs;    // ushort4 units
  for (int e = t; e < tot; e += 256) {
    const int g  = e & 31;
    const int rp = e >> 5;
    const int p  = rp % npairs;
    const int r  = rp / npairs;
    ushort4 vv = *(const ushort4*)&smem[r * 130 + g * 4];
    ushort4 sv = *(const ushort4*)&sbb[(size_t)(m0 + r) * 768 + (z + 1 + p) * 128 + g * 4];
    ushort4 o;
    o.x = f2bf(bf2f(vv.x) * bf2f(sv.x));
    o.y = f2bf(bf2f(vv.y) * bf2f(sv.y));
    o.z = f2bf(bf2f(vv.z) * bf2f(sv.z));
    o.w = f2bf(bf2f(vv.w) * bf2f(sv.w));
    *(ushort4*)&c[(size_t)(m0 + r) * 2688 + 768 + (size_t)(pb0[z] + p) * 128 + g * 4] = o;
  }
}

// ---------------------------------------------------------------------------
// Feature build: rows 0,1,2,3,5.  one wave per row; half-waves split seq.
// ---------------------------------------------------------------------------
__global__ __launch_bounds__(256)
void k_feat(const int* __restrict__ item_id, const int* __restrict__ likes,
            const int* __restrict__ views, const int* __restrict__ item_seq,
            const unsigned short* __restrict__ iembb, const float* __restrict__ cate_emb,
            unsigned short* __restrict__ xb)
{
  const int b = blockIdx.x * 4 + (threadIdx.x >> 6);
  const int lane = threadIdx.x & 63;
  const int half = lane >> 5, ql = lane & 31;
  const size_t base = (size_t)b * 768;
  const int li = likes[b], vi = views[b], id = item_id[b];

  int idxs[25];
  #pragma unroll
  for (int j = 0; j < 25; j++) idxs[j] = item_seq[b * 50 + half + 2 * j];

  float4 hs = make_float4(0.f, 0.f, 0.f, 0.f);
  float cnt = 0.f;
  #pragma unroll
  for (int j = 0; j < 25; j++) {
    const int idx = idxs[j];
    if (idx != 0) {
      cnt += 1.0f;
      ushort4 v = *(const ushort4*)&iembb[(size_t)idx * 128 + ql * 4];
      hs.x += bf2f(v.x); hs.y += bf2f(v.y); hs.z += bf2f(v.z); hs.w += bf2f(v.w);
    }
  }
  cnt  += __shfl_xor(cnt, 32, 64);
  hs.x += __shfl_xor(hs.x, 32, 64);
  hs.y += __shfl_xor(hs.y, 32, 64);
  hs.z += __shfl_xor(hs.z, 32, 64);
  hs.w += __shfl_xor(hs.w, 32, 64);
  const float ic = 1.0f / fmaxf(cnt, 1.0f);

  *(unsigned int*)&xb[base + lane * 2] = 0u;            // row 0 zeros

  {                                                     // rows 1,2 (like/view)
    const float4 v = *(const float4*)&cate_emb[(size_t)(half ? vi : li) * 128 + ql * 4];
    ushort4 o; o.x = f2bf(v.x); o.y = f2bf(v.y); o.z = f2bf(v.z); o.w = f2bf(v.w);
    *(ushort4*)&xb[base + 128 + half * 128 + ql * 4] = o;
  }
  if (half == 0) {                                      // row 3 (id)
    *(ushort4*)&xb[base + 384 + ql * 4] =
        *(const ushort4*)&iembb[(size_t)id * 128 + ql * 4];
  } else {                                              // row 5 (hist mean)
    ushort4 o; o.x = f2bf(hs.x * ic); o.y = f2bf(hs.y * ic);
               o.z = f2bf(hs.z * ic); o.w = f2bf(hs.w * ic);
    *(ushort4*)&xb[base + 640 + ql * 4] = o;
  }
}

// ---------------------------------------------------------------------------
// LayerNorm + exact GELU on y -> xb row 4 (img_feat). one wave per row.
// ---------------------------------------------------------------------------
__global__ __launch_bounds__(256)
void k_ln(const float* __restrict__ y, const float* __restrict__ ln_g,
          const float* __restrict__ ln_b, unsigned short* __restrict__ xb)
{
  const int b = blockIdx.x * 4 + (threadIdx.x >> 6);
  const int lane = threadIdx.x & 63;
  float v0 = y[(size_t)b * 128 + lane], v1 = y[(size_t)b * 128 + lane + 64];
  float s = v0 + v1, s2 = v0 * v0 + v1 * v1;
  #pragma unroll
  for (int o = 32; o > 0; o >>= 1) { s += __shfl_xor(s, o, 64); s2 += __shfl_xor(s2, o, 64); }
  float mu  = s * (1.0f / 128.0f);
  float var = s2 * (1.0f / 128.0f) - mu * mu;
  float rs  = rsqrtf(var + 1e-5f);
  float t0 = (v0 - mu) * rs * ln_g[lane]      + ln_b[lane];
  float t1 = (v1 - mu) * rs * ln_g[lane + 64] + ln_b[lane + 64];
  xb[(size_t)b * 768 + 512 + lane]      = f2bf(gelu_exact(t0));
  xb[(size_t)b * 768 + 512 + lane + 64] = f2bf(gelu_exact(t1));
}

// ---------------------------------------------------------------------------
// GAT attention + residual ELU + SE gate.  one wave per batch row.
// ---------------------------------------------------------------------------
__global__ __launch_bounds__(256)
void k_att(const unsigned short* __restrict__ hp, const unsigned short* __restrict__ xb,
           const float* __restrict__ gnn_a, const float* __restrict__ se_w1,
           const float* __restrict__ se_b1, const float* __restrict__ se_w2,
           const float* __restrict__ se_b2, unsigned short* __restrict__ c,
           unsigned short* __restrict__ sb)
{
  __shared__ float hps[4][6][128];
  __shared__ float eis[4][4][6], ejs[4][4][6];
  __shared__ float atts[4][4][6][6];
  const int wv = threadIdx.x >> 6, lane = threadIdx.x & 63;
  const int b = blockIdx.x * 4 + wv;

  #pragma unroll
  for (int n = 0; n < 6; n++) {
    unsigned int pk = *(const unsigned int*)&hp[((size_t)b * 6 + n) * 128 + lane * 2];
    float2 f; f.x = bf2f((unsigned short)(pk & 0xFFFFu));
              f.y = bf2f((unsigned short)(pk >> 16));
    *(float2*)&hps[wv][n][lane * 2] = f;
  }
  __syncthreads();

  if (lane < 24) {                      // (h,n) pairs: ei/ej dots over HD=32
    int h = lane & 3, n = lane >> 2;
    float e1 = 0.f, e2 = 0.f;
    for (int o = 0; o < 32; o++) {
      float v = hps[wv][n][h * 32 + o];
      e1 += v * gnn_a[h * 64 + o];
      e2 += v * gnn_a[h * 64 + 32 + o];
    }
    eis[wv][h][n] = e1; ejs[wv][h][n] = e2;
  }
  __syncthreads();

  if (lane < 24) {                      // per (h,i): leaky + softmax over j
    int h = lane & 3, i = lane >> 2;
    float ev[6]; float mx = -1e30f;
    #pragma unroll
    for (int j = 0; j < 6; j++) {
      float e = eis[wv][h][i] + ejs[wv][h][j];
      e = e > 0.f ? e : 0.2f * e;
      ev[j] = e; mx = fmaxf(mx, e);
    }
    float ssum = 0.f;
    #pragma unroll
    for (int j = 0; j < 6; j++) { ev[j] = expf(ev[j] - mx); ssum += ev[j]; }
    float inv = 1.0f / ssum;
    #pragma unroll
    for (int j = 0; j < 6; j++) atts[wv][h][i][j] = ev[j] * inv;
  }
  __syncthreads();

  const int h = lane >> 4;              // head of col pair (2l, 2l+1)
  float g0[6], g1[6], zz[6];
  #pragma unroll
  for (int n = 0; n < 6; n++) {
    float hn0 = 0.f, hn1 = 0.f;
    #pragma unroll
    for (int m = 0; m < 6; m++) {
      float a = atts[wv][h][n][m];
      float2 v = *(const float2*)&hps[wv][m][lane * 2];
      hn0 += a * v.x; hn1 += a * v.y;
    }
    unsigned int xp = *(const unsigned int*)&xb[(size_t)b * 768 + n * 128 + lane * 2];
    float a0 = hn0 + bf2f((unsigned short)(xp & 0xFFFFu));
    float a1 = hn1 + bf2f((unsigned short)(xp >> 16));
    a0 = a0 > 0.f ? a0 : expm1f(a0);
    a1 = a1 > 0.f ? a1 : expm1f(a1);
    g0[n] = a0; g1[n] = a1;
    float zacc = a0 + a1;
    #pragma unroll
    for (int o = 32; o > 0; o >>= 1) zacc += __shfl_xor(zacc, o, 64);
    zz[n] = zacc * (1.0f / 128.0f);
  }

  // SE gate (tiny 6->3->6 MLP, redundant per lane)
  float rr[3];
  #pragma unroll
  for (int j = 0; j < 3; j++) {
    float a = se_b1[j];
    #pragma unroll
    for (int n = 0; n < 6; n++) a += zz[n] * se_w1[n * 3 + j];
    rr[j] = fmaxf(a, 0.f);
  }
  float wse[6];
  #pragma unroll
  for (int n = 0; n < 6; n++) {
    float a = se_b2[n];
    #pragma unroll
    for (int j = 0; j < 3; j++) a += rr[j] * se_w2[j * 6 + n];
    wse[n] = 1.0f / (1.0f + expf(-a));
  }

  #pragma unroll
  for (int n = 0; n < 6; n++) {
    unsigned int pc = (unsigned int)f2bf(g0[n]) | ((unsigned int)f2bf(g1[n]) << 16);
    unsigned int ps = (unsigned int)f2bf(g0[n] * wse[n]) | ((unsigned int)f2bf(g1[n] * wse[n]) << 16);
    *(unsigned int*)&c[(size_t)b * 2688 + n * 128 + lane * 2]  = pc;
    *(unsigned int*)&sb[(size_t)b * 768 + n * 128 + lane * 2]  = ps;
  }
}

// ---------------------------------------------------------------------------
// Final 256-dot + sigmoid (h2 bf16). one wave per row.
// ---------------------------------------------------------------------------
__global__ __launch_bounds__(256)
void k_out(const unsigned short* __restrict__ h2, const float* __restrict__ w3,
           const float* __restrict__ b3, float* __restrict__ out)
{
  const int b = blockIdx.x * 4 + (threadIdx.x >> 6);
  const int lane = threadIdx.x & 63;
  ushort4 v = *(const ushort4*)&h2[(size_t)b * 256 + lane * 4];
  float a = bf2f(v.x) * w3[lane * 4]     + bf2f(v.y) * w3[lane * 4 + 1]
          + bf2f(v.z) * w3[lane * 4 + 2] + bf2f(v.w) * w3[lane * 4 + 3];
  #pragma unroll
  for (int o = 32; o > 0; o >>= 1) a += __shfl_xor(a, o, 64);
  if (lane == 0) out[b] = 1.0f / (1.0f + expf(-(a + b3[0])));
}

// ---------------------------------------------------------------------------
// Workspace layout (bytes). Aliases: y=sb region, h1=xb region. Peak ~203 MB.
// ---------------------------------------------------------------------------
#define OFF_MMWT   0ull           // 32768
#define OFF_WALLT  32768ull       // 32768
#define OFF_BIWT   65536ull       // 163840
#define OFF_W1T    229376ull      // 2752512
#define OFF_W2T    2981888ull     // 262144
#define OFF_IMMB   3244032ull     // 4194304
#define OFF_XB     7438336ull     // 25165824  (alias: h1 16777216 later)
#define OFF_HP     32604160ull    // 25165824  (bf16)
#define OFF_SB     57769984ull    // 25165824  (alias: y 8388608 earlier)
#define OFF_C      82935808ull    // 88080384
#define OFF_H2     171016192ull   // 8388608
#define OFF_IEMB   179404800ull   // 23479808 -> total 202884608

extern "C" void kernel_launch(void* const* d_in, const int* in_sizes, int n_in,
                              void* d_out, int out_size, void* d_ws, size_t ws_size,
                              hipStream_t stream)
{
  const int*   item_id  = (const int*)  d_in[0];
  const float* item_mm  = (const float*)d_in[1];
  const int*   likes    = (const int*)  d_in[2];
  const int*   views    = (const int*)  d_in[3];
  const int*   item_seq = (const int*)  d_in[4];
  const float* item_emb = (const float*)d_in[5];
  const float* cate_emb = (const float*)d_in[6];
  const float* mm_w     = (const float*)d_in[7];
  const float* mm_b     = (const float*)d_in[8];
  const float* ln_g     = (const float*)d_in[9];
  const float* ln_b     = (const float*)d_in[10];
  const float* gnn_W    = (const float*)d_in[11];
  const float* gnn_a    = (const float*)d_in[12];
  const float* se_w1    = (const float*)d_in[13];
  const float* se_b1    = (const float*)d_in[14];
  const float* se_w2    = (const float*)d_in[15];
  const float* se_b2    = (const float*)d_in[16];
  const float* bi_W     = (const float*)d_in[17];
  const float* mlp_w1   = (const float*)d_in[18];
  const float* mlp_b1   = (const float*)d_in[19];
  const float* bn1_g    = (const float*)d_in[20];
  const float* bn1_b    = (const float*)d_in[21];
  const float* mlp_w2   = (const float*)d_in[22];
  const float* mlp_b2   = (const float*)d_in[23];
  const float* bn2_g    = (const float*)d_in[24];
  const float* bn2_b    = (const float*)d_in[25];
  const float* mlp_w3   = (const float*)d_in[26];
  const float* mlp_b3   = (const float*)d_in[27];
  float* out = (float*)d_out;

  char* ws = (char*)d_ws;
  unsigned short* mmwt  = (unsigned short*)(ws + OFF_MMWT);
  unsigned short* wallt = (unsigned short*)(ws + OFF_WALLT);
  unsigned short* biwt  = (unsigned short*)(ws + OFF_BIWT);
  unsigned short* w1t   = (unsigned short*)(ws + OFF_W1T);
  unsigned short* w2t   = (unsigned short*)(ws + OFF_W2T);
  unsigned short* immb  = (unsigned short*)(ws + OFF_IMMB);
  unsigned short* xb    = (unsigned short*)(ws + OFF_XB);
  unsigned short* hpb   = (unsigned short*)(ws + OFF_HP);
  unsigned short* sbb   = (unsigned short*)(ws + OFF_SB);
  float*          yb    = (float*)         (ws + OFF_SB);   // alias: dead before sb
  unsigned short* cbuf  = (unsigned short*)(ws + OFF_C);
  unsigned short* h1b   = (unsigned short*)(ws + OFF_XB);   // alias: xb dead
  unsigned short* h2b   = (unsigned short*)(ws + OFF_H2);
  unsigned short* iembb = (unsigned short*)(ws + OFF_IEMB);

  // 1. packs + item_emb convert (merged)
  k_pack<<<4096, 256, 0, stream>>>(mm_w, gnn_W, bi_W, item_mm, item_emb,
                                   mmwt, wallt, biwt, immb, iembb);
  // 2-3. coalesced transposes of mlp_w1, mlp_w2
  k_transp<<<dim3(8, 42), 256, 0, stream>>>(mlp_w1, w1t, 2688, 512);
  k_transp<<<dim3(4, 8),  256, 0, stream>>>(mlp_w2, w2t, 512, 256);
  // 4. feature rows 0,1,2,3,5
  k_feat<<<BB / 4, 256, 0, stream>>>(item_id, likes, views, item_seq, iembb, cate_emb, xb);
  // 5. y = item_mm @ mm_w + mm_b   (BM=64: 256 blocks)
  gemm_bt<64, 0, false><<<dim3(1, 256), 512, 0, stream>>>(immb, 128, mmwt, 128,
      yb, 128, 128, mm_b, nullptr, nullptr);
  // 6. LN + GELU -> xb row 4
  k_ln<<<BB / 4, 256, 0, stream>>>(yb, ln_g, ln_b, xb);
  // 7. hp = x2d @ W_all (BM=128: 768 blocks, 3/CU x 8 waves)
  gemm_bt<128, 2, false><<<dim3(1, 768), 512, 0, stream>>>(xb, 128, wallt, 128,
      hpb, 128, 128, nullptr, nullptr, nullptr);
  // 8. attention + SE -> c[:, :768], sb
  k_att<<<BB / 4, 256, 0, stream>>>(hpb, xb, gnn_a, se_w1, se_b1, se_w2, se_b2, cbuf, sbb);
  // 9. vid GEMM + LDS-transposed pairs -> c[:, 768:]
  gemm_vid<<<dim3(1, 128, 5), 256, 0, stream>>>(sbb, biwt, cbuf);
  // 10. h1 = gelu(bn1(c @ w1 + b1))   (BM=128: 512 blocks, 2/CU x 8 waves)
  gemm_bt<128, 3, true><<<dim3(4, 128), 512, 0, stream>>>(cbuf, 2688, w1t, 2688,
      h1b, 512, 2688, mlp_b1, bn1_g, bn1_b);
  // 11. h2 = gelu(bn2(h1 @ w2 + b2))  (BM=64: 512 blocks)
  gemm_bt<64, 3, true><<<dim3(2, 256), 512, 0, stream>>>(h1b, 512, w2t, 512,
      h2b, 256, 512, mlp_b2, bn2_g, bn2_b);
  // 12. out = sigmoid(h2 @ w3 + b3)
  k_out<<<BB / 4, 256, 0, stream>>>(h2b, mlp_w3, mlp_b3, out);
}

// Round 6
// 347.242 us; speedup vs baseline: 1.3591x; 1.0067x over previous
//
#include <hip/hip_runtime.h>
#include <hip/hip_bf16.h>
#include <cstdint>
#include <cstddef>

#define BB 16384

typedef float  floatx4 __attribute__((ext_vector_type(4)));
typedef __bf16 bf16x8  __attribute__((ext_vector_type(8)));

__device__ __forceinline__ unsigned short f2bf(float f) {
  union { float f; unsigned int u; } v; v.f = f;
  unsigned int r = v.u + 0x7FFFu + ((v.u >> 16) & 1u);
  return (unsigned short)(r >> 16);
}
__device__ __forceinline__ float bf2f(unsigned short h) {
  union { unsigned int u; float f; } v; v.u = ((unsigned int)h) << 16;
  return v.f;
}
__device__ __forceinline__ float gelu_exact(float x) {
  return 0.5f * x * (1.0f + erff(x * 0.7071067811865475f));
}

// async global->LDS, 16B per lane; LDS dest = wave-uniform base + lane*16
#define ALOAD16(g, l) \
  __builtin_amdgcn_global_load_lds((const __attribute__((address_space(1))) void*)(g), \
                                   (__attribute__((address_space(3))) void*)(l), 16, 0, 0)

// ---------------------------------------------------------------------------
// Packs + item_emb bf16 convert: mm_w^T, gnn_W^T, bi_W^T, item_mm, item_emb
// ---------------------------------------------------------------------------
__global__ void k_pack(const float* __restrict__ mm_w, const float* __restrict__ gnn_W,
                       const float* __restrict__ bi_W, const float* __restrict__ item_mm,
                       const float* __restrict__ item_emb,
                       unsigned short* __restrict__ mmwt, unsigned short* __restrict__ wallt,
                       unsigned short* __restrict__ biwt, unsigned short* __restrict__ immb,
                       unsigned short* __restrict__ iembb)
{
  const int total = 2211840 + 2934976;
  for (int id = blockIdx.x * 256 + threadIdx.x; id < total; id += gridDim.x * 256) {
    if (id < 16384) {
      int n = id / 128, k = id % 128;
      mmwt[id] = f2bf(mm_w[k * 128 + n]);
    } else if (id < 32768) {
      int l = id - 16384; int nc = l / 128, k = l % 128;
      wallt[l] = f2bf(gnn_W[(nc >> 5) * 4096 + k * 32 + (nc & 31)]);
    } else if (id < 114688) {
      int l = id - 32768; int f = l / 16384, rr = l % 16384, e = rr / 128, d = rr % 128;
      biwt[l] = f2bf(bi_W[f * 16384 + d * 128 + e]);
    } else if (id < 2211840) {
      int l = id - 114688;
      immb[l] = f2bf(item_mm[l]);
    } else {
      int l = id - 2211840;
      float4 v = ((const float4*)item_emb)[l];
      ushort4 o; o.x = f2bf(v.x); o.y = f2bf(v.y); o.z = f2bf(v.z); o.w = f2bf(v.w);
      ((ushort4*)iembb)[l] = o;
    }
  }
}

// ---------------------------------------------------------------------------
// Merged LDS-tiled transposes: blocks 0..335 -> w1 (2688x512), 336..367 -> w2
// ---------------------------------------------------------------------------
__global__ __launch_bounds__(256)
void k_transp2(const float* __restrict__ w1, const float* __restrict__ w2,
               unsigned short* __restrict__ w1t, unsigned short* __restrict__ w2t)
{
  __shared__ float tile[64][65];
  int blk = blockIdx.x;
  const float* in; unsigned short* outp; int R, C, bx, by;
  if (blk < 336) { in = w1; outp = w1t; R = 2688; C = 512; bx = blk % 8; by = blk / 8; }
  else { blk -= 336; in = w2; outp = w2t; R = 512; C = 256; bx = blk % 4; by = blk / 4; }
  const int c0 = bx * 64, r0 = by * 64;
  const int lr = threadIdx.x >> 6;
  const int lc = threadIdx.x & 63;
  #pragma unroll
  for (int i = 0; i < 16; i++) {
    int r = lr + i * 4;
    tile[r][lc] = in[(size_t)(r0 + r) * C + c0 + lc];
  }
  __syncthreads();
  #pragma unroll
  for (int i = 0; i < 16; i++) {
    int c = lr + i * 4;
    outp[(size_t)(c0 + c) * R + r0 + lc] = f2bf(tile[lc][c]);
  }
}

// ---------------------------------------------------------------------------
// bf16 MFMA GEMM, 512 threads: C = A * Bt^T.  BM x 128 tile, BK=64,
// XOR-8 swizzled global_load_lds staging.  EPI 3 = bias+bn+gelu -> bf16.
// (used for MLP1 only now)
// ---------------------------------------------------------------------------
template<int BM, int EPI, bool SWZ>
__global__ __launch_bounds__(512)
void gemm_bt(const unsigned short* __restrict__ A, int lda,
             const unsigned short* __restrict__ Bt, int ldb,
             void* __restrict__ Cp, int ldc, int K,
             const float* __restrict__ bias, const float* __restrict__ bng,
             const float* __restrict__ bnb)
{
  constexpr int WGM = BM / 64;
  constexpr int WGN = 8 / WGM;
  constexpr int TN  = 128 / WGN;
  constexpr int NT  = TN / 16;
  constexpr int NRW = (BM + 128) / 8;
  constexpr int ISS = NRW / 8;

  int bx = blockIdx.x, by = blockIdx.y;
  if constexpr (SWZ) {
    int p = by * gridDim.x + bx;
    int xcd = p & 7, slot = p >> 3;
    bx = slot % gridDim.x;
    by = xcd * (gridDim.y >> 3) + slot / gridDim.x;
  }
  const int n0 = bx * 128;
  const int m0 = by * BM;
  __shared__ __align__(16) unsigned short As[BM * 64];
  __shared__ __align__(16) unsigned short Bs[128 * 64];
  const int t = threadIdx.x;
  const int lane = t & 63, w = t >> 6;
  const int wm = w % WGM, wn = w / WGM;
  const int lr = lane & 15, lq = lane >> 4;

  floatx4 acc[4][NT];
  #pragma unroll
  for (int a = 0; a < 4; a++)
    #pragma unroll
    for (int b = 0; b < NT; b++) acc[a][b] = (floatx4){0.f, 0.f, 0.f, 0.f};

  const int srow = lane >> 3;
  const int schk = (lane & 7) ^ srow;
  const int rb0 = w * NRW;

  for (int k0 = 0; k0 < K; k0 += 64) {
    __syncthreads();
    #pragma unroll
    for (int q = 0; q < ISS; q++) {
      const int rb = rb0 + q * 8;
      if (rb < BM) {
        ALOAD16(A + (size_t)(m0 + rb + srow) * lda + k0 + schk * 8, As + rb * 64);
      } else {
        const int rbb = rb - BM;
        ALOAD16(Bt + (size_t)(n0 + rbb + srow) * ldb + k0 + schk * 8, Bs + rbb * 64);
      }
    }
    __syncthreads();
    #pragma unroll
    for (int ko = 0; ko < 2; ko++) {
      bf16x8 af[4], bfv[NT];
      #pragma unroll
      for (int mt = 0; mt < 4; mt++) {
        const int row = wm * 64 + mt * 16 + lr;
        const int pc = (ko * 4 + lq) ^ (lr & 7);
        af[mt] = __builtin_bit_cast(bf16x8, *(const uint4*)&As[row * 64 + pc * 8]);
      }
      #pragma unroll
      for (int nt = 0; nt < NT; nt++) {
        const int row = wn * TN + nt * 16 + lr;
        const int pc = (ko * 4 + lq) ^ (lr & 7);
        bfv[nt] = __builtin_bit_cast(bf16x8, *(const uint4*)&Bs[row * 64 + pc * 8]);
      }
      #pragma unroll
      for (int mt = 0; mt < 4; mt++)
        #pragma unroll
        for (int nt = 0; nt < NT; nt++)
          acc[mt][nt] = __builtin_amdgcn_mfma_f32_16x16x32_bf16(af[mt], bfv[nt], acc[mt][nt], 0, 0, 0);
    }
  }

  #pragma unroll
  for (int mt = 0; mt < 4; mt++)
    #pragma unroll
    for (int nt = 0; nt < NT; nt++)
      #pragma unroll
      for (int i = 0; i < 4; i++) {
        const int cm = m0 + wm * 64 + mt * 16 + lq * 4 + i;
        const int cn = n0 + wn * TN + nt * 16 + lr;
        float v = acc[mt][nt][i];
        size_t idx = (size_t)cm * ldc + cn;
        float tt = v + bias[cn];
        tt = tt * (bng[cn] * 0.9999950000374997f) + bnb[cn];
        ((unsigned short*)Cp)[idx] = f2bf(gelu_exact(tt));
      }
}

// ---------------------------------------------------------------------------
// Fused: y = item_mm @ mm_w + b  ->  LayerNorm  ->  GELU  -> xb row 4.
// 512 thr, BM=64, N=128, K=128.  C tile via LDS (stride 130), per-row shfl LN.
// ---------------------------------------------------------------------------
__global__ __launch_bounds__(512)
void k_mmln(const unsigned short* __restrict__ A, const unsigned short* __restrict__ Bt,
            const float* __restrict__ mm_b, const float* __restrict__ ln_g,
            const float* __restrict__ ln_b, unsigned short* __restrict__ xb)
{
  __shared__ __align__(16) char smem[64 * 130 * 4];    // 33280 B; staging 24576 aliased
  unsigned short* As = (unsigned short*)smem;           // 64*64
  unsigned short* Bs = (unsigned short*)(smem + 8192);  // 128*64
  float* cls = (float*)smem;                            // 64*130 after barrier

  const int t = threadIdx.x, lane = t & 63, w = t >> 6;
  const int lr = lane & 15, lq = lane >> 4;
  const int m0 = blockIdx.x * 64;

  floatx4 acc[4];
  #pragma unroll
  for (int a = 0; a < 4; a++) acc[a] = (floatx4){0.f, 0.f, 0.f, 0.f};

  const int srow = lane >> 3;
  const int schk = (lane & 7) ^ srow;
  const int rb0 = w * 24;

  for (int k0 = 0; k0 < 128; k0 += 64) {
    __syncthreads();
    #pragma unroll
    for (int q = 0; q < 3; q++) {
      const int rb = rb0 + q * 8;
      if (rb < 64) ALOAD16(A + (size_t)(m0 + rb + srow) * 128 + k0 + schk * 8, As + rb * 64);
      else { const int rbb = rb - 64; ALOAD16(Bt + (size_t)(rbb + srow) * 128 + k0 + schk * 8, Bs + rbb * 64); }
    }
    __syncthreads();
    #pragma unroll
    for (int ko = 0; ko < 2; ko++) {
      bf16x8 af[4], bv;
      #pragma unroll
      for (int mt = 0; mt < 4; mt++) {
        const int row = mt * 16 + lr;
        const int pc = (ko * 4 + lq) ^ (lr & 7);
        af[mt] = __builtin_bit_cast(bf16x8, *(const uint4*)&As[row * 64 + pc * 8]);
      }
      {
        const int row = w * 16 + lr;
        const int pc = (ko * 4 + lq) ^ (lr & 7);
        bv = __builtin_bit_cast(bf16x8, *(const uint4*)&Bs[row * 64 + pc * 8]);
      }
      #pragma unroll
      for (int mt = 0; mt < 4; mt++)
        acc[mt] = __builtin_amdgcn_mfma_f32_16x16x32_bf16(af[mt], bv, acc[mt], 0, 0, 0);
    }
  }

  __syncthreads();                     // staging dead; reuse as C tile
  #pragma unroll
  for (int mt = 0; mt < 4; mt++)
    #pragma unroll
    for (int i = 0; i < 4; i++) {
      const int rr = mt * 16 + lq * 4 + i;
      const int cc = w * 16 + lr;
      cls[rr * 130 + cc] = acc[mt][i] + mm_b[cc];
    }
  __syncthreads();

  const float2 g2 = *(const float2*)&ln_g[lane * 2];
  const float2 b2 = *(const float2*)&ln_b[lane * 2];
  #pragma unroll
  for (int rr = 0; rr < 8; rr++) {
    const int r = w * 8 + rr;
    float2 v = *(const float2*)&cls[r * 130 + lane * 2];
    float s = v.x + v.y, s2 = v.x * v.x + v.y * v.y;
    #pragma unroll
    for (int o = 32; o > 0; o >>= 1) { s += __shfl_xor(s, o, 64); s2 += __shfl_xor(s2, o, 64); }
    float mu  = s * (1.0f / 128.0f);
    float var = s2 * (1.0f / 128.0f) - mu * mu;
    float rs  = rsqrtf(var + 1e-5f);
    float t0 = gelu_exact((v.x - mu) * rs * g2.x + b2.x);
    float t1 = gelu_exact((v.y - mu) * rs * g2.y + b2.y);
    unsigned int pk = (unsigned int)f2bf(t0) | ((unsigned int)f2bf(t1) << 16);
    *(unsigned int*)&xb[(size_t)(m0 + r) * 768 + 512 + lane * 2] = pk;
  }
}

// ---------------------------------------------------------------------------
// Fused: hp = x2d @ W_all (GEMM 96x128x128) -> GAT attention + ELU + SE ->
// c[:, :768] and sb.  grid 1024 blocks x 256 thr; block = 16 batches.
// LDS: staging 28 KB aliased with hp tile 96x130 fp32 + att scratch = 52992 B.
// ---------------------------------------------------------------------------
__global__ __launch_bounds__(256)
void k_hpatt(const unsigned short* __restrict__ xb, const unsigned short* __restrict__ wallt,
             const float* __restrict__ gnn_a, const float* __restrict__ se_w1,
             const float* __restrict__ se_b1, const float* __restrict__ se_w2,
             const float* __restrict__ se_b2, unsigned short* __restrict__ c,
             unsigned short* __restrict__ sb)
{
  __shared__ __align__(16) char smem[52992];
  unsigned short* As = (unsigned short*)smem;            // 96*64
  unsigned short* Bs = (unsigned short*)(smem + 12288);  // 128*64
  float* hps  = (float*)smem;                            // 96*130 after barrier
  float* eis  = (float*)(smem + 49920);                  // [4][4][6]
  float* ejs  = eis + 96;                                // [4][4][6]
  float* atts = ejs + 96;                                // [4][4][6][6]

  const int t = threadIdx.x, lane = t & 63, w = t >> 6;
  const int wm = w & 1, wn = w >> 1;
  const int lr = lane & 15, lq = lane >> 4;
  const int m0 = blockIdx.x * 96;

  floatx4 acc[3][4];
  #pragma unroll
  for (int a = 0; a < 3; a++)
    #pragma unroll
    for (int b = 0; b < 4; b++) acc[a][b] = (floatx4){0.f, 0.f, 0.f, 0.f};

  const int srow = lane >> 3;
  const int schk = (lane & 7) ^ srow;
  const int rb0 = w * 56;

  for (int k0 = 0; k0 < 128; k0 += 64) {
    __syncthreads();
    #pragma unroll
    for (int q = 0; q < 7; q++) {
      const int rb = rb0 + q * 8;
      if (rb < 96) ALOAD16(xb + (size_t)(m0 + rb + srow) * 128 + k0 + schk * 8, As + rb * 64);
      else { const int rbb = rb - 96; ALOAD16(wallt + (size_t)(rbb + srow) * 128 + k0 + schk * 8, Bs + rbb * 64); }
    }
    __syncthreads();
    #pragma unroll
    for (int ko = 0; ko < 2; ko++) {
      bf16x8 af[3], bfv[4];
      #pragma unroll
      for (int mt = 0; mt < 3; mt++) {
        const int row = wm * 48 + mt * 16 + lr;
        const int pc = (ko * 4 + lq) ^ (lr & 7);
        af[mt] = __builtin_bit_cast(bf16x8, *(const uint4*)&As[row * 64 + pc * 8]);
      }
      #pragma unroll
      for (int nt = 0; nt < 4; nt++) {
        const int row = wn * 64 + nt * 16 + lr;
        const int pc = (ko * 4 + lq) ^ (lr & 7);
        bfv[nt] = __builtin_bit_cast(bf16x8, *(const uint4*)&Bs[row * 64 + pc * 8]);
      }
      #pragma unroll
      for (int mt = 0; mt < 3; mt++)
        #pragma unroll
        for (int nt = 0; nt < 4; nt++)
          acc[mt][nt] = __builtin_amdgcn_mfma_f32_16x16x32_bf16(af[mt], bfv[nt], acc[mt][nt], 0, 0, 0);
    }
  }

  __syncthreads();                     // staging dead; write hp tile
  #pragma unroll
  for (int mt = 0; mt < 3; mt++)
    #pragma unroll
    for (int nt = 0; nt < 4; nt++)
      #pragma unroll
      for (int i = 0; i < 4; i++) {
        const int rr = wm * 48 + mt * 16 + lq * 4 + i;
        const int cc = wn * 64 + nt * 16 + lr;
        hps[rr * 130 + cc] = acc[mt][nt][i];
      }
  __syncthreads();

  // attention: wave w handles local batches w*4 .. w*4+3 sequentially
  for (int it = 0; it < 4; it++) {
    const int lb = w * 4 + it;
    const int b = blockIdx.x * 16 + lb;
    const float* hb = hps + lb * 6 * 130;

    if (lane < 24) {                    // ei/ej dots over HD=32
      int h = lane & 3, n = lane >> 2;
      float e1 = 0.f, e2 = 0.f;
      for (int o = 0; o < 32; o++) {
        float v = hb[n * 130 + h * 32 + o];
        e1 += v * gnn_a[h * 64 + o];
        e2 += v * gnn_a[h * 64 + 32 + o];
      }
      eis[w * 24 + h * 6 + n] = e1; ejs[w * 24 + h * 6 + n] = e2;
    }
    if (lane < 24) {                    // leaky + softmax over j (per h,i)
      int h = lane & 3, i = lane >> 2;
      float ev[6]; float mx = -1e30f;
      #pragma unroll
      for (int j = 0; j < 6; j++) {
        float e = eis[w * 24 + h * 6 + i] + ejs[w * 24 + h * 6 + j];
        e = e > 0.f ? e : 0.2f * e;
        ev[j] = e; mx = fmaxf(mx, e);
      }
      float ssum = 0.f;
      #pragma unroll
      for (int j = 0; j < 6; j++) { ev[j] = expf(ev[j] - mx); ssum += ev[j]; }
      float inv = 1.0f / ssum;
      #pragma unroll
      for (int j = 0; j < 6; j++) atts[w * 144 + h * 36 + i * 6 + j] = ev[j] * inv;
    }

    const int hh = lane >> 4;           // head of col pair (2l, 2l+1)
    float g0[6], g1[6], zz[6];
    #pragma unroll
    for (int n = 0; n < 6; n++) {
      float hn0 = 0.f, hn1 = 0.f;
      #pragma unroll
      for (int m = 0; m < 6; m++) {
        float a = atts[w * 144 + hh * 36 + n * 6 + m];
        float2 v = *(const float2*)&hb[m * 130 + lane * 2];
        hn0 += a * v.x; hn1 += a * v.y;
      }
      unsigned int xp = *(const unsigned int*)&xb[(size_t)b * 768 + n * 128 + lane * 2];
      float a0 = hn0 + bf2f((unsigned short)(xp & 0xFFFFu));
      float a1 = hn1 + bf2f((unsigned short)(xp >> 16));
      a0 = a0 > 0.f ? a0 : expm1f(a0);
      a1 = a1 > 0.f ? a1 : expm1f(a1);
      g0[n] = a0; g1[n] = a1;
      float zacc = a0 + a1;
      #pragma unroll
      for (int o = 32; o > 0; o >>= 1) zacc += __shfl_xor(zacc, o, 64);
      zz[n] = zacc * (1.0f / 128.0f);
    }

    float rr3[3];
    #pragma unroll
    for (int j = 0; j < 3; j++) {
      float a = se_b1[j];
      #pragma unroll
      for (int n = 0; n < 6; n++) a += zz[n] * se_w1[n * 3 + j];
      rr3[j] = fmaxf(a, 0.f);
    }
    float wse[6];
    #pragma unroll
    for (int n = 0; n < 6; n++) {
      float a = se_b2[n];
      #pragma unroll
      for (int j = 0; j < 3; j++) a += rr3[j] * se_w2[j * 6 + n];
      wse[n] = 1.0f / (1.0f + expf(-a));
    }

    #pragma unroll
    for (int n = 0; n < 6; n++) {
      unsigned int pc = (unsigned int)f2bf(g0[n]) | ((unsigned int)f2bf(g1[n]) << 16);
      unsigned int ps = (unsigned int)f2bf(g0[n] * wse[n]) | ((unsigned int)f2bf(g1[n] * wse[n]) << 16);
      *(unsigned int*)&c[(size_t)b * 2688 + n * 128 + lane * 2]  = pc;
      *(unsigned int*)&sb[(size_t)b * 768 + n * 128 + lane * 2]  = ps;
    }
  }
}

// ---------------------------------------------------------------------------
// vid GEMM + pairs, LDS-transposed epilogue (unchanged from R5)
// ---------------------------------------------------------------------------
__global__ __launch_bounds__(256)
void gemm_vid(const unsigned short* __restrict__ sbb, const unsigned short* __restrict__ biwt,
              unsigned short* __restrict__ c)
{
  const int z = blockIdx.z;
  const int m0 = blockIdx.y * 128;
  __shared__ __align__(16) unsigned short smem[128 * 130];
  unsigned short* As = smem;
  unsigned short* Bs = smem + 8192;
  const int t = threadIdx.x;
  const int lane = t & 63, w = t >> 6;
  const int wm = w & 1, wn = w >> 1;
  const int lr = lane & 15, lq = lane >> 4;

  floatx4 acc[4][4];
  #pragma unroll
  for (int a = 0; a < 4; a++)
    #pragma unroll
    for (int b = 0; b < 4; b++) acc[a][b] = (floatx4){0.f, 0.f, 0.f, 0.f};

  const int srow = lane >> 3;
  const int schk = (lane & 7) ^ srow;
  const unsigned short* Ag = sbb + (size_t)(m0 + w * 32 + srow) * 768 + z * 128 + schk * 8;
  const unsigned short* Bg = biwt + z * 16384 + (size_t)(w * 32 + srow) * 128 + schk * 8;
  unsigned short* AsW = As + w * 32 * 64;
  unsigned short* BsW = Bs + w * 32 * 64;

  for (int k0 = 0; k0 < 128; k0 += 64) {
    __syncthreads();
    #pragma unroll
    for (int q = 0; q < 4; q++) {
      ALOAD16(Ag + k0 + (size_t)(q * 8) * 768, AsW + q * 512);
      ALOAD16(Bg + k0 + (size_t)(q * 8) * 128, BsW + q * 512);
    }
    __syncthreads();
    #pragma unroll
    for (int ko = 0; ko < 2; ko++) {
      bf16x8 af[4], bfv[4];
      #pragma unroll
      for (int mt = 0; mt < 4; mt++) {
        const int row = wm * 64 + mt * 16 + lr;
        const int pc = (ko * 4 + lq) ^ (lr & 7);
        af[mt] = __builtin_bit_cast(bf16x8, *(const uint4*)&As[row * 64 + pc * 8]);
      }
      #pragma unroll
      for (int nt = 0; nt < 4; nt++) {
        const int row = wn * 64 + nt * 16 + lr;
        const int pc = (ko * 4 + lq) ^ (lr & 7);
        bfv[nt] = __builtin_bit_cast(bf16x8, *(const uint4*)&Bs[row * 64 + pc * 8]);
      }
      #pragma unroll
      for (int mt = 0; mt < 4; mt++)
        #pragma unroll
        for (int nt = 0; nt < 4; nt++)
          acc[mt][nt] = __builtin_amdgcn_mfma_f32_16x16x32_bf16(af[mt], bfv[nt], acc[mt][nt], 0, 0, 0);
    }
  }

  __syncthreads();
  #pragma unroll
  for (int mt = 0; mt < 4; mt++)
    #pragma unroll
    for (int nt = 0; nt < 4; nt++)
      #pragma unroll
      for (int i = 0; i < 4; i++) {
        const int rr = wm * 64 + mt * 16 + lq * 4 + i;
        const int cc = wn * 64 + nt * 16 + lr;
        smem[rr * 130 + cc] = f2bf(acc[mt][nt][i]);
      }
  __syncthreads();

  const int pb0[5] = {0, 5, 9, 12, 14};
  const int npairs = 5 - z;
  const int tot = 128 * 32 * npairs;
  for (int e = t; e < tot; e += 256) {
    const int g  = e & 31;
    const int rp = e >> 5;
    const int p  = rp % npairs;
    const int r  = rp / npairs;
    ushort4 vv = *(const ushort4*)&smem[r * 130 + g * 4];
    ushort4 sv = *(const ushort4*)&sbb[(size_t)(m0 + r) * 768 + (z + 1 + p) * 128 + g * 4];
    ushort4 o;
    o.x = f2bf(bf2f(vv.x) * bf2f(sv.x));
    o.y = f2bf(bf2f(vv.y) * bf2f(sv.y));
    o.z = f2bf(bf2f(vv.z) * bf2f(sv.z));
    o.w = f2bf(bf2f(vv.w) * bf2f(sv.w));
    *(ushort4*)&c[(size_t)(m0 + r) * 2688 + 768 + (size_t)(pb0[z] + p) * 128 + g * 4] = o;
  }
}

// ---------------------------------------------------------------------------
// Feature build: rows 0,1,2,3,5 (unchanged from R5)
// ---------------------------------------------------------------------------
__global__ __launch_bounds__(256)
void k_feat(const int* __restrict__ item_id, const int* __restrict__ likes,
            const int* __restrict__ views, const int* __restrict__ item_seq,
            const unsigned short* __restrict__ iembb, const float* __restrict__ cate_emb,
            unsigned short* __restrict__ xb)
{
  const int b = blockIdx.x * 4 + (threadIdx.x >> 6);
  const int lane = threadIdx.x & 63;
  const int half = lane >> 5, ql = lane & 31;
  const size_t base = (size_t)b * 768;
  const int li = likes[b], vi = views[b], id = item_id[b];

  int idxs[25];
  #pragma unroll
  for (int j = 0; j < 25; j++) idxs[j] = item_seq[b * 50 + half + 2 * j];

  float4 hs = make_float4(0.f, 0.f, 0.f, 0.f);
  float cnt = 0.f;
  #pragma unroll
  for (int j = 0; j < 25; j++) {
    const int idx = idxs[j];
    if (idx != 0) {
      cnt += 1.0f;
      ushort4 v = *(const ushort4*)&iembb[(size_t)idx * 128 + ql * 4];
      hs.x += bf2f(v.x); hs.y += bf2f(v.y); hs.z += bf2f(v.z); hs.w += bf2f(v.w);
    }
  }
  cnt  += __shfl_xor(cnt, 32, 64);
  hs.x += __shfl_xor(hs.x, 32, 64);
  hs.y += __shfl_xor(hs.y, 32, 64);
  hs.z += __shfl_xor(hs.z, 32, 64);
  hs.w += __shfl_xor(hs.w, 32, 64);
  const float ic = 1.0f / fmaxf(cnt, 1.0f);

  *(unsigned int*)&xb[base + lane * 2] = 0u;

  {
    const float4 v = *(const float4*)&cate_emb[(size_t)(half ? vi : li) * 128 + ql * 4];
    ushort4 o; o.x = f2bf(v.x); o.y = f2bf(v.y); o.z = f2bf(v.z); o.w = f2bf(v.w);
    *(ushort4*)&xb[base + 128 + half * 128 + ql * 4] = o;
  }
  if (half == 0) {
    *(ushort4*)&xb[base + 384 + ql * 4] =
        *(const ushort4*)&iembb[(size_t)id * 128 + ql * 4];
  } else {
    ushort4 o; o.x = f2bf(hs.x * ic); o.y = f2bf(hs.y * ic);
               o.z = f2bf(hs.z * ic); o.w = f2bf(hs.w * ic);
    *(ushort4*)&xb[base + 640 + ql * 4] = o;
  }
}

// ---------------------------------------------------------------------------
// Fused MLP2 + bn+gelu + final 256-dot + sigmoid -> out.
// 512 thr, BM=64, BN=256 (full rows in-block), K=512.  grid 256 blocks.
// ---------------------------------------------------------------------------
__global__ __launch_bounds__(512)
void k_mlp2out(const unsigned short* __restrict__ A, const unsigned short* __restrict__ Bt,
               const float* __restrict__ b2v, const float* __restrict__ bng,
               const float* __restrict__ bnb, const float* __restrict__ w3,
               const float* __restrict__ b3, float* __restrict__ out)
{
  __shared__ __align__(16) char smem[40960];            // staging; h2 tile 33792 aliased
  unsigned short* As = (unsigned short*)smem;           // 64*64
  unsigned short* Bs = (unsigned short*)(smem + 8192);  // 256*64
  unsigned short* h2s = (unsigned short*)smem;          // 64*264 after final barrier

  const int t = threadIdx.x, lane = t & 63, w = t >> 6;
  const int lr = lane & 15, lq = lane >> 4;
  const int m0 = blockIdx.x * 64;

  floatx4 acc[4][2];
  #pragma unroll
  for (int a = 0; a < 4; a++)
    #pragma unroll
    for (int b = 0; b < 2; b++) acc[a][b] = (floatx4){0.f, 0.f, 0.f, 0.f};

  const int srow = lane >> 3;
  const int schk = (lane & 7) ^ srow;
  const int rb0 = w * 40;

  for (int k0 = 0; k0 < 512; k0 += 64) {
    __syncthreads();
    #pragma unroll
    for (int q = 0; q < 5; q++) {
      const int rb = rb0 + q * 8;
      if (rb < 64) ALOAD16(A + (size_t)(m0 + rb + srow) * 512 + k0 + schk * 8, As + rb * 64);
      else { const int rbb = rb - 64; ALOAD16(Bt + (size_t)(rbb + srow) * 512 + k0 + schk * 8, Bs + rbb * 64); }
    }
    __syncthreads();
    #pragma unroll
    for (int ko = 0; ko < 2; ko++) {
      bf16x8 af[4], bfv[2];
      #pragma unroll
      for (int mt = 0; mt < 4; mt++) {
        const int row = mt * 16 + lr;
        const int pc = (ko * 4 + lq) ^ (lr & 7);
        af[mt] = __builtin_bit_cast(bf16x8, *(const uint4*)&As[row * 64 + pc * 8]);
      }
      #pragma unroll
      for (int nt = 0; nt < 2; nt++) {
        const int row = w * 32 + nt * 16 + lr;
        const int pc = (ko * 4 + lq) ^ (lr & 7);
        bfv[nt] = __builtin_bit_cast(bf16x8, *(const uint4*)&Bs[row * 64 + pc * 8]);
      }
      #pragma unroll
      for (int mt = 0; mt < 4; mt++)
        #pragma unroll
        for (int nt = 0; nt < 2; nt++)
          acc[mt][nt] = __builtin_amdgcn_mfma_f32_16x16x32_bf16(af[mt], bfv[nt], acc[mt][nt], 0, 0, 0);
    }
  }

  __syncthreads();                     // staging dead; write h2 tile (bf16)
  #pragma unroll
  for (int mt = 0; mt < 4; mt++)
    #pragma unroll
    for (int nt = 0; nt < 2; nt++)
      #pragma unroll
      for (int i = 0; i < 4; i++) {
        const int rr = mt * 16 + lq * 4 + i;
        const int cc = w * 32 + nt * 16 + lr;
        float tt = acc[mt][nt][i] + b2v[cc];
        tt = tt * (bng[cc] * 0.9999950000374997f) + bnb[cc];
        h2s[rr * 264 + cc] = f2bf(gelu_exact(tt));
      }
  __syncthreads();

  const float4 w4 = *(const float4*)&w3[lane * 4];
  #pragma unroll
  for (int rr = 0; rr < 8; rr++) {
    const int r = w * 8 + rr;
    ushort4 v = *(const ushort4*)&h2s[r * 264 + lane * 4];
    float a = bf2f(v.x) * w4.x + bf2f(v.y) * w4.y + bf2f(v.z) * w4.z + bf2f(v.w) * w4.w;
    #pragma unroll
    for (int o = 32; o > 0; o >>= 1) a += __shfl_xor(a, o, 64);
    if (lane == 0) out[m0 + r] = 1.0f / (1.0f + expf(-(a + b3[0])));
  }
}

// ---------------------------------------------------------------------------
// Workspace layout (bytes).  h1 aliases xb region (xb dead after k_hpatt... 
// kept distinct slots as before; xb reused for h1).  Peak ~203 MB.
// ---------------------------------------------------------------------------
#define OFF_MMWT   0ull           // 32768
#define OFF_WALLT  32768ull       // 32768
#define OFF_BIWT   65536ull       // 163840
#define OFF_W1T    229376ull      // 2752512
#define OFF_W2T    2981888ull     // 262144
#define OFF_IMMB   3244032ull     // 4194304
#define OFF_XB     7438336ull     // 25165824  (alias: h1 16777216 later)
#define OFF_SB     57769984ull    // 25165824
#define OFF_C      82935808ull    // 88080384
#define OFF_IEMB   179404800ull   // 23479808 -> total 202884608

extern "C" void kernel_launch(void* const* d_in, const int* in_sizes, int n_in,
                              void* d_out, int out_size, void* d_ws, size_t ws_size,
                              hipStream_t stream)
{
  const int*   item_id  = (const int*)  d_in[0];
  const float* item_mm  = (const float*)d_in[1];
  const int*   likes    = (const int*)  d_in[2];
  const int*   views    = (const int*)  d_in[3];
  const int*   item_seq = (const int*)  d_in[4];
  const float* item_emb = (const float*)d_in[5];
  const float* cate_emb = (const float*)d_in[6];
  const float* mm_w     = (const float*)d_in[7];
  const float* mm_b     = (const float*)d_in[8];
  const float* ln_g     = (const float*)d_in[9];
  const float* ln_b     = (const float*)d_in[10];
  const float* gnn_W    = (const float*)d_in[11];
  const float* gnn_a    = (const float*)d_in[12];
  const float* se_w1    = (const float*)d_in[13];
  const float* se_b1    = (const float*)d_in[14];
  const float* se_w2    = (const float*)d_in[15];
  const float* se_b2    = (const float*)d_in[16];
  const float* bi_W     = (const float*)d_in[17];
  const float* mlp_w1   = (const float*)d_in[18];
  const float* mlp_b1   = (const float*)d_in[19];
  const float* bn1_g    = (const float*)d_in[20];
  const float* bn1_b    = (const float*)d_in[21];
  const float* mlp_w2   = (const float*)d_in[22];
  const float* mlp_b2   = (const float*)d_in[23];
  const float* bn2_g    = (const float*)d_in[24];
  const float* bn2_b    = (const float*)d_in[25];
  const float* mlp_w3   = (const float*)d_in[26];
  const float* mlp_b3   = (const float*)d_in[27];
  float* out = (float*)d_out;

  char* ws = (char*)d_ws;
  unsigned short* mmwt  = (unsigned short*)(ws + OFF_MMWT);
  unsigned short* wallt = (unsigned short*)(ws + OFF_WALLT);
  unsigned short* biwt  = (unsigned short*)(ws + OFF_BIWT);
  unsigned short* w1t   = (unsigned short*)(ws + OFF_W1T);
  unsigned short* w2t   = (unsigned short*)(ws + OFF_W2T);
  unsigned short* immb  = (unsigned short*)(ws + OFF_IMMB);
  unsigned short* xb    = (unsigned short*)(ws + OFF_XB);
  unsigned short* sbb   = (unsigned short*)(ws + OFF_SB);
  unsigned short* cbuf  = (unsigned short*)(ws + OFF_C);
  unsigned short* h1b   = (unsigned short*)(ws + OFF_XB);   // alias: xb dead after k_hpatt
  unsigned short* iembb = (unsigned short*)(ws + OFF_IEMB);

  // 1. packs + item_emb convert
  k_pack<<<4096, 256, 0, stream>>>(mm_w, gnn_W, bi_W, item_mm, item_emb,
                                   mmwt, wallt, biwt, immb, iembb);
  // 2. merged transposes of mlp_w1, mlp_w2
  k_transp2<<<368, 256, 0, stream>>>(mlp_w1, mlp_w2, w1t, w2t);
  // 3. feature rows 0,1,2,3,5
  k_feat<<<BB / 4, 256, 0, stream>>>(item_id, likes, views, item_seq, iembb, cate_emb, xb);
  // 4. fused mm GEMM + bias + LN + GELU -> xb row 4
  k_mmln<<<256, 512, 0, stream>>>(immb, mmwt, mm_b, ln_g, ln_b, xb);
  // 5. fused hp GEMM + attention + SE -> c[:, :768], sb
  k_hpatt<<<1024, 256, 0, stream>>>(xb, wallt, gnn_a, se_w1, se_b1, se_w2, se_b2, cbuf, sbb);
  // 6. vid GEMM + pairs -> c[:, 768:]
  gemm_vid<<<dim3(1, 128, 5), 256, 0, stream>>>(sbb, biwt, cbuf);
  // 7. h1 = gelu(bn1(c @ w1 + b1))
  gemm_bt<128, 3, true><<<dim3(4, 128), 512, 0, stream>>>(cbuf, 2688, w1t, 2688,
      h1b, 512, 2688, mlp_b1, bn1_g, bn1_b);
  // 8. fused MLP2 + bn + gelu + dot(w3) + sigmoid -> out
  k_mlp2out<<<256, 512, 0, stream>>>(h1b, w2t, mlp_b2, bn2_g, bn2_b, mlp_w3, mlp_b3, out);
}